// Round 1
// baseline (578.543 us; speedup 1.0000x reference)
//
#include <hip/hip_runtime.h>

// ---------------------------------------------------------------------------
// AttentiveModes (S=16, C=1024, H=16, DH=32) on MI355X.
// Round 13: eliminate the standalone weight-conversion pass (k_cvt6, ~203us).
// Mode-0 GEMMs (templated <M0=true>) read fp32 weights directly in the exact
// fragment layout, convert in-register (same RNE f2bf), feed MFMA, and store
// the swizzled bf16 chunks for modes 1-2 (only mh==0 waves store; each chunk
// stored exactly once). Saves the 335 MB bf16 round-trip (write-then-reread)
// and the serial conversion kernel; conversion now overlaps MFMA.
// ---------------------------------------------------------------------------

#define C1024 1024
#define D512  512
#define FF4096 4096
#define NELEM 32768.0f
#define EPSLN 1e-5f
#define QSCALE 0.17677669529663687f  // 1/sqrt(32)

typedef __attribute__((ext_vector_type(8))) short bf16x8;
typedef __attribute__((ext_vector_type(4))) float f32x4;
typedef unsigned short u16;

__device__ inline u16 f2bf(float f) {
    unsigned u = __float_as_uint(f);
    u += 0x7fffu + ((u >> 16) & 1u);
    return (u16)(u >> 16);
}

__device__ inline bf16x8 cvt8(f32x4 a, f32x4 b) {
    bf16x8 r;
    r[0] = (short)f2bf(a[0]); r[1] = (short)f2bf(a[1]);
    r[2] = (short)f2bf(a[2]); r[3] = (short)f2bf(a[3]);
    r[4] = (short)f2bf(b[0]); r[5] = (short)f2bf(b[1]);
    r[6] = (short)f2bf(b[2]); r[7] = (short)f2bf(b[3]);
    return r;
}

// swizzled-weight inner loop: p pre-offset by lane*8; 1KB/frag contiguous.
__device__ inline void mmz(const u16* __restrict__ act, const u16* __restrict__ p,
                           int nkk, f32x4& acc0, f32x4& acc1) {
#pragma unroll 4
    for (int j = 0; j < nkk; ++j) {
        bf16x8 aF = *(const bf16x8*)(act + j * 32);
        bf16x8 b0 = *(const bf16x8*)(p + (size_t)j * 1024);
        bf16x8 b1 = *(const bf16x8*)(p + (size_t)j * 1024 + 512);
        acc0 = __builtin_amdgcn_mfma_f32_16x16x32_bf16(aF, b0, acc0, 0, 0, 0);
        acc1 = __builtin_amdgcn_mfma_f32_16x16x32_bf16(aF, b1, acc1, 0, 0, 0);
    }
}

// fused fp32->bf16 weight inner loop (mode 0).
// w32: pre-offset to row (ntile*32 + lr), k-offset (k0 + kg*8); row stride K.
//      Lane (kg,lr) supplies B-fragment n=lr (b0) and n=16+lr (b1).
// w16c: swizzled chunk base + lane*8 (same pointer mmz would read).
// st:  true for exactly one wave per chunk (mh==0) -> each chunk stored once.
__device__ inline void mmz_cvt(const u16* __restrict__ act,
                               const float* __restrict__ w32, int K,
                               u16* __restrict__ w16c, bool st,
                               int nkk, f32x4& acc0, f32x4& acc1) {
    const float* w32b = w32 + (size_t)16 * K;   // rows n+16 (b=1 half)
#pragma unroll 2
    for (int j = 0; j < nkk; ++j) {
        bf16x8 aF = *(const bf16x8*)(act + j * 32);
        f32x4 l0 = *(const f32x4*)(w32 + j * 32);
        f32x4 h0 = *(const f32x4*)(w32 + j * 32 + 4);
        f32x4 l1 = *(const f32x4*)(w32b + j * 32);
        f32x4 h1 = *(const f32x4*)(w32b + j * 32 + 4);
        bf16x8 b0 = cvt8(l0, h0);
        bf16x8 b1 = cvt8(l1, h1);
        if (st) {
            *(bf16x8*)(w16c + (size_t)j * 1024) = b0;
            *(bf16x8*)(w16c + (size_t)j * 1024 + 512) = b1;
        }
        acc0 = __builtin_amdgcn_mfma_f32_16x16x32_bf16(aF, b0, acc0, 0, 0, 0);
        acc1 = __builtin_amdgcn_mfma_f32_16x16x32_bf16(aF, b1, acc1, 0, 0, 0);
    }
}

// 256-thread block reduce of (s,q); lds >= 10 floats.
__device__ inline void reduce256(float& s, float& q, int t, float* lds) {
    for (int off = 32; off; off >>= 1) {
        s += __shfl_down(s, off, 64);
        q += __shfl_down(q, off, 64);
    }
    int wv = t >> 6;
    if ((t & 63) == 0) { lds[wv * 2] = s; lds[wv * 2 + 1] = q; }
    __syncthreads();
    if (t == 0) {
        lds[8] = lds[0] + lds[2] + lds[4] + lds[6];
        lds[9] = lds[1] + lds[3] + lds[5] + lds[7];
    }
    __syncthreads();
    s = lds[8]; q = lds[9];
}

// ---- LN1: gather from two slab bases, redundant stats, apply lx/ly --------
__global__ void k_ln1(const float* __restrict__ s1, const float* __restrict__ s2,
                      const float* __restrict__ gw, const float* __restrict__ gb,
                      const float* __restrict__ hw, const float* __restrict__ hb,
                      float* __restrict__ a_buf,
                      u16* __restrict__ xn, u16* __restrict__ yn) {
    __shared__ float lds[10];
    int i = blockIdx.x, cb = blockIdx.y, t = threadIdx.x;
    float s = 0.f, q = 0.f;
#pragma unroll 4
    for (int rr = 0; rr < 32; ++rr) {
        const float* src = (rr < 16)
            ? (s1 + ((i * 16 + rr) << 10))
            : (s2 + (((rr - 16) * 16 + i) << 10));
        f32x4 v = *(const f32x4*)(src + t * 4);
        s += v[0] + v[1] + v[2] + v[3];
        q += v[0]*v[0] + v[1]*v[1] + v[2]*v[2] + v[3]*v[3];
        if ((t >> 5) == cb)
            *(f32x4*)(a_buf + ((i * 32 + rr) << 10) + t * 4) = v;
    }
    reduce256(s, q, t, lds);
    float mean = s * (1.f / NELEM);
    float var = q * (1.f / NELEM) - mean * mean;
    float inv = rsqrtf(var + EPSLN);
    int c = cb * 128 + (t & 31) * 4;
    int r0 = (t >> 5) * 4;
#pragma unroll
    for (int rr = 0; rr < 4; ++rr) {
        int row = r0 + rr;
        const float* src = (row < 16)
            ? (s1 + ((i * 16 + row) << 10))
            : (s2 + (((row - 16) * 16 + i) << 10));
        f32x4 v = *(const f32x4*)(src + c);
        int base = ((i * 32 + row) << 10) + c;
        f32x4 gwv = *(const f32x4*)(gw + base);
        f32x4 gbv = *(const f32x4*)(gb + base);
        f32x4 hwv = *(const f32x4*)(hw + base);
        f32x4 hbv = *(const f32x4*)(hb + base);
        float z0 = (v[0]-mean)*inv, z1 = (v[1]-mean)*inv, z2 = (v[2]-mean)*inv, z3 = (v[3]-mean)*inv;
        uint2 a, b;
        a.x = (unsigned)f2bf(z0*gwv[0]+gbv[0]) | ((unsigned)f2bf(z1*gwv[1]+gbv[1]) << 16);
        a.y = (unsigned)f2bf(z2*gwv[2]+gbv[2]) | ((unsigned)f2bf(z3*gwv[3]+gbv[3]) << 16);
        b.x = (unsigned)f2bf(z0*hwv[0]+hbv[0]) | ((unsigned)f2bf(z1*hwv[1]+hbv[1]) << 16);
        b.y = (unsigned)f2bf(z2*hwv[2]+hbv[2]) | ((unsigned)f2bf(z3*hwv[3]+hbv[3]) << 16);
        *(uint2*)(xn + base) = a;
        *(uint2*)(yn + base) = b;
    }
}

// ---- LN2: stats over x1 (redundant per block), apply lf -> lnf ------------
__global__ void k_ln2(const float* __restrict__ x1,
                      const float* __restrict__ gw, const float* __restrict__ gb,
                      u16* __restrict__ out) {
    __shared__ float lds[10];
    int i = blockIdx.x, cb = blockIdx.y, t = threadIdx.x;
    float s = 0.f, q = 0.f;
#pragma unroll 4
    for (int rr = 0; rr < 32; ++rr) {
        f32x4 v = *(const f32x4*)(x1 + ((i * 32 + rr) << 10) + t * 4);
        s += v[0] + v[1] + v[2] + v[3];
        q += v[0]*v[0] + v[1]*v[1] + v[2]*v[2] + v[3]*v[3];
    }
    reduce256(s, q, t, lds);
    float mean = s * (1.f / NELEM);
    float var = q * (1.f / NELEM) - mean * mean;
    float inv = rsqrtf(var + EPSLN);
    int c = cb * 128 + (t & 31) * 4;
    int r0 = (t >> 5) * 4;
#pragma unroll
    for (int rr = 0; rr < 4; ++rr) {
        int base = ((i * 32 + r0 + rr) << 10) + c;
        f32x4 v  = *(const f32x4*)(x1 + base);
        f32x4 gwv = *(const f32x4*)(gw + base);
        f32x4 gbv = *(const f32x4*)(gb + base);
        float z0 = (v[0]-mean)*inv, z1 = (v[1]-mean)*inv, z2 = (v[2]-mean)*inv, z3 = (v[3]-mean)*inv;
        uint2 a;
        a.x = (unsigned)f2bf(z0*gwv[0]+gbv[0]) | ((unsigned)f2bf(z1*gwv[1]+gbv[1]) << 16);
        a.y = (unsigned)f2bf(z2*gwv[2]+gbv[2]) | ((unsigned)f2bf(z3*gwv[3]+gbv[3]) << 16);
        *(uint2*)(out + base) = a;
    }
}

// ---- QKV GEMM (swizzled chunks), in-block split-K2: 512 thr ---------------
template<bool M0>
__global__ void __launch_bounds__(512, 4)
k_gemm_qkv(const u16* __restrict__ xn, const u16* __restrict__ yn,
           u16* __restrict__ wq, const float* __restrict__ wqb,
           u16* __restrict__ wk, const float* __restrict__ wkb,
           u16* __restrict__ wv, const float* __restrict__ wvb,
           const float* __restrict__ wq32, const float* __restrict__ wk32,
           const float* __restrict__ wv32,
           u16* __restrict__ qo, u16* __restrict__ ko, u16* __restrict__ vT) {
    __shared__ float Pl[2][32][64];
    int bx = blockIdx.x, i = blockIdx.y;
    int w = threadIdx.x >> 6, lane = threadIdx.x & 63;
    int kh = w >> 2, mh = (w >> 1) & 1, wn = w & 1;
    int lr = lane & 15, kg = lane >> 4;
    int sel = bx >> 3;
    int ntl = (bx - sel * 8) * 2 + wn;
    const u16* act = (sel == 0 ? xn : yn) + (i * 32 + mh * 16 + lr) * C1024 + kh * 512 + kg * 8;
    u16* Wm = (sel == 0 ? wq : (sel == 1 ? wk : wv));
    u16* p = Wm + (((size_t)i * 16 + ntl) * 32 + kh * 16) * 1024 + lane * 8;
    f32x4 a0 = {0.f, 0.f, 0.f, 0.f}, a1 = {0.f, 0.f, 0.f, 0.f};
    if constexpr (M0) {
        const float* W32 = (sel == 0 ? wq32 : (sel == 1 ? wk32 : wv32));
        const float* pw = W32 + ((size_t)i * 512 + ntl * 32 + lr) * 1024 + kh * 512 + kg * 8;
        mmz_cvt(act, pw, 1024, p, mh == 0, 16, a0, a1);
    } else {
        mmz(act, p, 16, a0, a1);
    }
    int m0 = mh * 16 + kg * 4;
#pragma unroll
    for (int r = 0; r < 4; ++r) {
        Pl[kh][m0 + r][wn * 32 + lr] = a0[r];
        Pl[kh][m0 + r][wn * 32 + 16 + lr] = a1[r];
    }
    __syncthreads();
    int t = threadIdx.x;
    int row = t >> 4, c0 = (t & 15) * 4;
    int nloc = bx * 64 - sel * 512 + c0;
    const float* bias = (sel == 0 ? wqb : (sel == 1 ? wkb : wvb)) + i * D512 + nloc;
    float v0 = Pl[0][row][c0]     + Pl[1][row][c0]     + bias[0];
    float v1 = Pl[0][row][c0 + 1] + Pl[1][row][c0 + 1] + bias[1];
    float v2 = Pl[0][row][c0 + 2] + Pl[1][row][c0 + 2] + bias[2];
    float v3 = Pl[0][row][c0 + 3] + Pl[1][row][c0 + 3] + bias[3];
    if (sel == 0) {
        uint2 a;
        a.x = (unsigned)f2bf(v0 * QSCALE) | ((unsigned)f2bf(v1 * QSCALE) << 16);
        a.y = (unsigned)f2bf(v2 * QSCALE) | ((unsigned)f2bf(v3 * QSCALE) << 16);
        *(uint2*)(qo + (i * 32 + row) * D512 + nloc) = a;
    } else if (sel == 1) {
        uint2 a;
        a.x = (unsigned)f2bf(v0) | ((unsigned)f2bf(v1) << 16);
        a.y = (unsigned)f2bf(v2) | ((unsigned)f2bf(v3) << 16);
        *(uint2*)(ko + (i * 32 + row) * D512 + nloc) = a;
    } else {
        int h = nloc >> 5, d = nloc & 31;
        u16* vb = vT + ((i * 16 + h) * 32 + d) * 32 + row;
        vb[0]  = f2bf(v0);
        vb[32] = f2bf(v1);
        vb[64] = f2bf(v2);
        vb[96] = f2bf(v3);
    }
}

// ---- attention per (idx, head) --------------------------------------------
__global__ void k_attn(const u16* __restrict__ q, const u16* __restrict__ k,
                       const u16* __restrict__ vT, u16* __restrict__ o) {
    __shared__ __align__(16) u16 Sm[4][32][32];
    int i = blockIdx.x;
    int w = threadIdx.x >> 6, lane = threadIdx.x & 63;
    int h = blockIdx.y * 4 + w;
    int lr = lane & 15, kg = lane >> 4;
    const u16* qb = q + i * 32 * D512 + h * 32 + kg * 8;
    const u16* kb = k + i * 32 * D512 + h * 32 + kg * 8;
    bf16x8 a0 = *(const bf16x8*)(qb + lr * D512);
    bf16x8 a1 = *(const bf16x8*)(qb + (16 + lr) * D512);
    bf16x8 b0 = *(const bf16x8*)(kb + lr * D512);
    bf16x8 b1 = *(const bf16x8*)(kb + (16 + lr) * D512);
    f32x4 z = {0.f, 0.f, 0.f, 0.f};
    f32x4 s00 = __builtin_amdgcn_mfma_f32_16x16x32_bf16(a0, b0, z, 0, 0, 0);
    f32x4 s01 = __builtin_amdgcn_mfma_f32_16x16x32_bf16(a0, b1, z, 0, 0, 0);
    f32x4 s10 = __builtin_amdgcn_mfma_f32_16x16x32_bf16(a1, b0, z, 0, 0, 0);
    f32x4 s11 = __builtin_amdgcn_mfma_f32_16x16x32_bf16(a1, b1, z, 0, 0, 0);
    int mr = kg * 4;
#pragma unroll
    for (int r = 0; r < 4; ++r) {
        Sm[w][mr + r][lr]           = f2bf(s00[r]);
        Sm[w][mr + r][16 + lr]      = f2bf(s01[r]);
        Sm[w][16 + mr + r][lr]      = f2bf(s10[r]);
        Sm[w][16 + mr + r][16 + lr] = f2bf(s11[r]);
    }
    __syncthreads();
    bf16x8 p0 = *(const bf16x8*)&Sm[w][lr][kg * 8];
    bf16x8 p1 = *(const bf16x8*)&Sm[w][16 + lr][kg * 8];
    const u16* vb = vT + (i * 16 + h) * 32 * 32 + kg * 8;
    bf16x8 v0 = *(const bf16x8*)(vb + lr * 32);
    bf16x8 v1 = *(const bf16x8*)(vb + (16 + lr) * 32);
    f32x4 o00 = __builtin_amdgcn_mfma_f32_16x16x32_bf16(p0, v0, z, 0, 0, 0);
    f32x4 o01 = __builtin_amdgcn_mfma_f32_16x16x32_bf16(p0, v1, z, 0, 0, 0);
    f32x4 o10 = __builtin_amdgcn_mfma_f32_16x16x32_bf16(p1, v0, z, 0, 0, 0);
    f32x4 o11 = __builtin_amdgcn_mfma_f32_16x16x32_bf16(p1, v1, z, 0, 0, 0);
#pragma unroll
    for (int r = 0; r < 4; ++r) {
        o[(i * 32 + mr + r) * D512 + h * 32 + lr]           = f2bf(o00[r]);
        o[(i * 32 + mr + r) * D512 + h * 32 + 16 + lr]      = f2bf(o01[r]);
        o[(i * 32 + 16 + mr + r) * D512 + h * 32 + lr]      = f2bf(o10[r]);
        o[(i * 32 + 16 + mr + r) * D512 + h * 32 + 16 + lr] = f2bf(o11[r]);
    }
}

// ---- w1 GEMM (swizzled chunks), in-block split-K2: 512 thr ----------------
template<bool M0>
__global__ void __launch_bounds__(512, 4)
k_gemm_w1(const u16* __restrict__ ob, u16* __restrict__ W,
          const float* __restrict__ W32, const float* __restrict__ bias,
          const float* __restrict__ a_buf, float* __restrict__ x1) {
    __shared__ float Pl[2][32][64];
    int bx = blockIdx.x, i = blockIdx.y;
    int w = threadIdx.x >> 6, lane = threadIdx.x & 63;
    int kh = w >> 2, mh = (w >> 1) & 1, wn = w & 1;
    int lr = lane & 15, kg = lane >> 4;
    int nt = bx * 2 + wn;
    const u16* act = ob + (i * 32 + mh * 16 + lr) * D512 + kh * 256 + kg * 8;
    u16* p = W + (((size_t)i * 32 + nt) * 16 + kh * 8) * 1024 + lane * 8;
    f32x4 a0 = {0.f, 0.f, 0.f, 0.f}, a1 = {0.f, 0.f, 0.f, 0.f};
    if constexpr (M0) {
        const float* pw = W32 + ((size_t)i * 1024 + nt * 32 + lr) * 512 + kh * 256 + kg * 8;
        mmz_cvt(act, pw, 512, p, mh == 0, 8, a0, a1);
    } else {
        mmz(act, p, 8, a0, a1);
    }
    int m0 = mh * 16 + kg * 4;
#pragma unroll
    for (int r = 0; r < 4; ++r) {
        Pl[kh][m0 + r][wn * 32 + lr] = a0[r];
        Pl[kh][m0 + r][wn * 32 + 16 + lr] = a1[r];
    }
    __syncthreads();
    int t = threadIdx.x;
    int row = t >> 4, c0 = (t & 15) * 4;
    int n = bx * 64 + c0;
    int base = ((i * 32 + row) << 10) + n;
    f32x4 bv = *(const f32x4*)(bias + i * C1024 + n);
    f32x4 av = *(const f32x4*)(a_buf + base);
    f32x4 r;
    r[0] = Pl[0][row][c0]     + Pl[1][row][c0]     + bv[0] + av[0];
    r[1] = Pl[0][row][c0 + 1] + Pl[1][row][c0 + 1] + bv[1] + av[1];
    r[2] = Pl[0][row][c0 + 2] + Pl[1][row][c0 + 2] + bv[2] + av[2];
    r[3] = Pl[0][row][c0 + 3] + Pl[1][row][c0 + 3] + bv[3] + av[3];
    *(f32x4*)(x1 + base) = r;
}

// ---- w2 GEMM (swizzled chunks): grid (64,16), 256 thr ---------------------
template<bool M0>
__global__ void __launch_bounds__(256, 4)
k_gemm_w2(const u16* __restrict__ lnf, u16* __restrict__ W,
          const float* __restrict__ W32, const float* __restrict__ bias,
          u16* __restrict__ hb) {
    int bx = blockIdx.x, i = blockIdx.y;
    int w = threadIdx.x >> 6, lane = threadIdx.x & 63;
    int mh = w & 1, wn = w >> 1, lr = lane & 15, kg = lane >> 4;
    int nt = bx * 2 + wn;
    const u16* act = lnf + (i * 32 + mh * 16 + lr) * C1024 + kg * 8;
    u16* p = W + (((size_t)i * 128 + nt) * 32) * 1024 + lane * 8;
    f32x4 a0 = {0.f, 0.f, 0.f, 0.f}, a1 = {0.f, 0.f, 0.f, 0.f};
    if constexpr (M0) {
        const float* pw = W32 + ((size_t)i * 4096 + nt * 32 + lr) * 1024 + kg * 8;
        mmz_cvt(act, pw, 1024, p, mh == 0, 32, a0, a1);
    } else {
        mmz(act, p, 32, a0, a1);
    }
    int m0 = mh * 16 + kg * 4;
    int nb = bx * 64 + wn * 32;
    int n0 = nb + lr, n1 = nb + 16 + lr;
    float b0 = bias[i * FF4096 + n0], b1 = bias[i * FF4096 + n1];
#pragma unroll
    for (int r = 0; r < 4; ++r) {
        float t0 = a0[r] + b0;
        float t1 = a1[r] + b1;
        float g0 = 0.5f * t0 * (1.f + erff(t0 * 0.70710678118654752f));
        float g1 = 0.5f * t1 * (1.f + erff(t1 * 0.70710678118654752f));
        hb[(i * 32 + m0 + r) * FF4096 + n0] = f2bf(g0);
        hb[(i * 32 + m0 + r) * FF4096 + n1] = f2bf(g1);
    }
}

// ---- w3 GEMM (swizzled chunks), in-block split-K4: 1024 thr ---------------
template<bool M0>
__global__ void __launch_bounds__(1024, 4)
k_gemm_w3(const u16* __restrict__ hb, u16* __restrict__ W,
          const float* __restrict__ W32, const float* __restrict__ bias,
          const float* __restrict__ x1, float* __restrict__ xout, int m1, int m2) {
    __shared__ float Pl[4][32][64];
    int bx = blockIdx.x, i = blockIdx.y;
    int w = threadIdx.x >> 6, lane = threadIdx.x & 63;
    int kq = w >> 2, mh = (w >> 1) & 1, wn = w & 1;
    int lr = lane & 15, kg = lane >> 4;
    int nt = bx * 2 + wn;
    const u16* act = hb + (i * 32 + mh * 16 + lr) * FF4096 + kq * 1024 + kg * 8;
    u16* p = W + (((size_t)i * 32 + nt) * 128 + kq * 32) * 1024 + lane * 8;
    f32x4 a0 = {0.f, 0.f, 0.f, 0.f}, a1 = {0.f, 0.f, 0.f, 0.f};
    if constexpr (M0) {
        const float* pw = W32 + ((size_t)i * 1024 + nt * 32 + lr) * 4096 + kq * 1024 + kg * 8;
        mmz_cvt(act, pw, 4096, p, mh == 0, 32, a0, a1);
    } else {
        mmz(act, p, 32, a0, a1);
    }
    int m0 = mh * 16 + kg * 4;
#pragma unroll
    for (int r = 0; r < 4; ++r) {
        Pl[kq][m0 + r][wn * 32 + lr] = a0[r];
        Pl[kq][m0 + r][wn * 32 + 16 + lr] = a1[r];
    }
    __syncthreads();
    int t = threadIdx.x;
    int row = t >> 5, c0 = (t & 31) * 2;
    int n = bx * 64 + c0;
    int dst = (row < 16) ? (((m1 * 16 + i) * 16 + row) << 10)
                         : (((m2 * 16 + i) * 16 + (row - 16)) << 10);
    int base = ((i * 32 + row) << 10) + n;
#pragma unroll
    for (int j = 0; j < 2; ++j) {
        float v = Pl[0][row][c0 + j] + Pl[1][row][c0 + j]
                + Pl[2][row][c0 + j] + Pl[3][row][c0 + j]
                + bias[i * C1024 + n + j] + x1[base + j];
        xout[dst + n + j] = v;
    }
}

// ---------------------------------------------------------------------------
extern "C" void kernel_launch(void* const* d_in, const int* in_sizes, int n_in,
                              void* d_out, int out_size, void* d_ws, size_t ws_size,
                              hipStream_t stream) {
    const float* x_in = (const float*)d_in[0];
    const float* lx_w = (const float*)d_in[1];
    const float* lx_b = (const float*)d_in[2];
    const float* ly_w = (const float*)d_in[3];
    const float* ly_b = (const float*)d_in[4];
    const float* lf_w = (const float*)d_in[5];
    const float* lf_b = (const float*)d_in[6];
    const float* wq_w = (const float*)d_in[7];
    const float* wq_b = (const float*)d_in[8];
    const float* wk_w = (const float*)d_in[9];
    const float* wk_b = (const float*)d_in[10];
    const float* wv_w = (const float*)d_in[11];
    const float* wv_b = (const float*)d_in[12];
    const float* w1   = (const float*)d_in[13];
    const float* b1   = (const float*)d_in[14];
    const float* w2   = (const float*)d_in[15];
    const float* b2   = (const float*)d_in[16];
    const float* w3   = (const float*)d_in[17];
    const float* b3   = (const float*)d_in[18];

    float* xbuf = (float*)d_out;   // working state x [3][16][16][1024]
    char* ws = (char*)d_ws;
    float* a_buf  = (float*)(ws);                          //  2 MB @ 0
    float* x1_buf = (float*)(ws + (2u << 20));             //  2 MB @ 2
    u16*   xn     = (u16*)(ws + (4u << 20));               //  1 MB @ 4
    u16*   yn     = (u16*)(ws + (5u << 20));               //  1 MB @ 5
    u16*   lnf    = (u16*)(ws + (6u << 20));               //  1 MB @ 6
    u16*   qb     = (u16*)(ws + (7u << 20));               // .5 MB @ 7
    u16*   kb     = (u16*)(ws + 7 * (1u << 20) + (1u << 19));
    u16*   vT     = (u16*)(ws + (8u << 20));               // .5 MB @ 8
    u16*   ob     = (u16*)(ws + 8 * (1u << 20) + (1u << 19));
    u16*   hbuf   = (u16*)(ws + (9u << 20));               //  4 MB @ 9
    u16*   wq16   = (u16*)(ws + (16u  << 20));             // 16 MB @ 16
    u16*   wk16   = (u16*)(ws + (32u  << 20));             // 16 MB @ 32
    u16*   wv16   = (u16*)(ws + (48u  << 20));             // 16 MB @ 48
    u16*   w1_16  = (u16*)(ws + (64u  << 20));             // 16 MB @ 64
    u16*   w2_16  = (u16*)(ws + (80u  << 20));             // 128 MB @ 80
    u16*   w3_16  = (u16*)(ws + (208u << 20));             // 128 MB @ 208

    const size_t SLAB = (size_t)16 * 16 * 1024;
    const int modes[3][2] = {{0, 1}, {2, 0}, {1, 2}};
    for (int mi = 0; mi < 3; ++mi) {
        int m1 = modes[mi][0], m2 = modes[mi][1];
        const float* s1 = (mi == 2) ? (xbuf + m1 * SLAB) : (x_in + m1 * SLAB);
        const float* s2 = (mi == 0) ? (x_in + m2 * SLAB) : (xbuf + m2 * SLAB);
        k_ln1<<<dim3(16, 8), 256, 0, stream>>>(s1, s2, lx_w, lx_b, ly_w, ly_b, a_buf, xn, yn);
        if (mi == 0) {
            k_gemm_qkv<true><<<dim3(24, 16), 512, 0, stream>>>(
                xn, yn, wq16, wq_b, wk16, wk_b, wv16, wv_b,
                wq_w, wk_w, wv_w, qb, kb, vT);
        } else {
            k_gemm_qkv<false><<<dim3(24, 16), 512, 0, stream>>>(
                xn, yn, wq16, wq_b, wk16, wk_b, wv16, wv_b,
                nullptr, nullptr, nullptr, qb, kb, vT);
        }
        k_attn<<<dim3(16, 4), 256, 0, stream>>>(qb, kb, vT, ob);
        if (mi == 0) {
            k_gemm_w1<true><<<dim3(16, 16), 512, 0, stream>>>(ob, w1_16, w1, b1, a_buf, x1_buf);
        } else {
            k_gemm_w1<false><<<dim3(16, 16), 512, 0, stream>>>(ob, w1_16, nullptr, b1, a_buf, x1_buf);
        }
        k_ln2<<<dim3(16, 8), 256, 0, stream>>>(x1_buf, lf_w, lf_b, lnf);
        if (mi == 0) {
            k_gemm_w2<true><<<dim3(64, 16), 256, 0, stream>>>(lnf, w2_16, w2, b2, hbuf);
        } else {
            k_gemm_w2<false><<<dim3(64, 16), 256, 0, stream>>>(lnf, w2_16, nullptr, b2, hbuf);
        }
        if (mi == 0) {
            k_gemm_w3<true><<<dim3(16, 16), 1024, 0, stream>>>(hbuf, w3_16, w3, b3, x1_buf, xbuf, m1, m2);
        } else {
            k_gemm_w3<false><<<dim3(16, 16), 1024, 0, stream>>>(hbuf, w3_16, nullptr, b3, x1_buf, xbuf, m1, m2);
        }
    }
}

// Round 2
// 562.384 us; speedup vs baseline: 1.0287x; 1.0287x over previous
//
#include <hip/hip_runtime.h>

// ---------------------------------------------------------------------------
// AttentiveModes (S=16, C=1024, H=16, DH=32) on MI355X.
// Round 14: revert R13's fused in-GEMM conversion (regressed: strided fp32
// fragment reads + duplicated mh reads + store on MFMA path). Back to R12's
// wave-contiguous streaming converter, but INTERLEAVED with mode-0 consumers
// for L3 (256MB Infinity Cache) reuse: each weight is converted immediately
// before the GEMM that first reads it; w2/w3 are split into two N-halves so
// each cvt-half + gemm-half phase's working set (201MB) fits in L3. Mode-0
// bf16 weight reads become L3 hits instead of HBM re-reads (~335MB saved).
// ---------------------------------------------------------------------------

#define C1024 1024
#define D512  512
#define FF4096 4096
#define NELEM 32768.0f
#define EPSLN 1e-5f
#define QSCALE 0.17677669529663687f  // 1/sqrt(32)
#define LP 258                        // LDS pitch in f32 words

typedef __attribute__((ext_vector_type(8))) short bf16x8;
typedef __attribute__((ext_vector_type(4))) float f32x4;
typedef unsigned short u16;

__device__ inline u16 f2bf(float f) {
    unsigned u = __float_as_uint(f);
    u += 0x7fffu + ((u >> 16) & 1u);
    return (u16)(u >> 16);
}

__device__ inline bf16x8 cvt8(f32x4 a, f32x4 b) {
    bf16x8 r;
    r[0] = (short)f2bf(a[0]); r[1] = (short)f2bf(a[1]);
    r[2] = (short)f2bf(a[2]); r[3] = (short)f2bf(a[3]);
    r[4] = (short)f2bf(b[0]); r[5] = (short)f2bf(b[1]);
    r[6] = (short)f2bf(b[2]); r[7] = (short)f2bf(b[3]);
    return r;
}

// ---- weight converter (R12 structure, single weight, nt-range param) ------
// Tile = (i,nt,kz): 32 rows x 256 k fp32. Phase 1: thread (row=t>>3, c8=t&7)
// loads f32x4 at col c8*4+32j (each 8-lane row-group = 128B contiguous per
// instruction). Phase 2: output map (o = p*2048 + t*8), decode to
// (c,b,kg,lr), read 8 f32 from LDS, write bf16x8 -> consecutive-lane 16B.
__global__ void __launch_bounds__(256, 4)
k_cvt(const float* __restrict__ S, u16* __restrict__ D,
      int N32, int kzs, int ntOff, int ntCnt) {
    __shared__ float lds[32 * LP];    // 33 KB
    int bid = blockIdx.x;
    int kz = bid % kzs;
    int nt = ntOff + (bid / kzs) % ntCnt;
    int i  = bid / (kzs * ntCnt);
    int K = kzs * 256;
    int t = threadIdx.x;
    // phase 1: contiguous wave reads
    int row = t >> 3, c8 = t & 7;
    const float* Sp = S + ((size_t)(i * N32 + nt) * 32 + row) * K + kz * 256 + c8 * 4;
    float* Lrow = lds + row * LP + c8 * 4;
#pragma unroll
    for (int j = 0; j < 8; ++j) {
        f32x4 v = *(const f32x4*)(Sp + 32 * j);
        Lrow[32 * j]     = v[0];
        Lrow[32 * j + 1] = v[1];
        Lrow[32 * j + 2] = v[2];
        Lrow[32 * j + 3] = v[3];
    }
    __syncthreads();
    // phase 2: chunk-ordered conversion + linear global writes
    u16* Dp = D + (((size_t)i * N32 + nt) * (kzs * 8) + kz * 8) * 1024;
#pragma unroll
    for (int p = 0; p < 4; ++p) {
        int o = p * 2048 + t * 8;
        int c  = o >> 10;
        int b  = (o >> 9) & 1;
        int kg = (o >> 7) & 3;
        int lr = (o >> 3) & 15;
        const float* src = lds + (b * 16 + lr) * LP + c * 32 + kg * 8;
        f32x4 lo, hi;
        lo[0] = src[0]; lo[1] = src[1]; lo[2] = src[2]; lo[3] = src[3];
        hi[0] = src[4]; hi[1] = src[5]; hi[2] = src[6]; hi[3] = src[7];
        *(bf16x8*)(Dp + o) = cvt8(lo, hi);
    }
}

// swizzled-weight inner loop: p pre-offset by lane*8; 1KB/frag contiguous.
__device__ inline void mmz(const u16* __restrict__ act, const u16* __restrict__ p,
                           int nkk, f32x4& acc0, f32x4& acc1) {
#pragma unroll 4
    for (int j = 0; j < nkk; ++j) {
        bf16x8 aF = *(const bf16x8*)(act + j * 32);
        bf16x8 b0 = *(const bf16x8*)(p + (size_t)j * 1024);
        bf16x8 b1 = *(const bf16x8*)(p + (size_t)j * 1024 + 512);
        acc0 = __builtin_amdgcn_mfma_f32_16x16x32_bf16(aF, b0, acc0, 0, 0, 0);
        acc1 = __builtin_amdgcn_mfma_f32_16x16x32_bf16(aF, b1, acc1, 0, 0, 0);
    }
}

// 256-thread block reduce of (s,q); lds >= 10 floats.
__device__ inline void reduce256(float& s, float& q, int t, float* lds) {
    for (int off = 32; off; off >>= 1) {
        s += __shfl_down(s, off, 64);
        q += __shfl_down(q, off, 64);
    }
    int wv = t >> 6;
    if ((t & 63) == 0) { lds[wv * 2] = s; lds[wv * 2 + 1] = q; }
    __syncthreads();
    if (t == 0) {
        lds[8] = lds[0] + lds[2] + lds[4] + lds[6];
        lds[9] = lds[1] + lds[3] + lds[5] + lds[7];
    }
    __syncthreads();
    s = lds[8]; q = lds[9];
}

// ---- LN1: gather from two slab bases, redundant stats, apply lx/ly --------
__global__ void k_ln1(const float* __restrict__ s1, const float* __restrict__ s2,
                      const float* __restrict__ gw, const float* __restrict__ gb,
                      const float* __restrict__ hw, const float* __restrict__ hb,
                      float* __restrict__ a_buf,
                      u16* __restrict__ xn, u16* __restrict__ yn) {
    __shared__ float lds[10];
    int i = blockIdx.x, cb = blockIdx.y, t = threadIdx.x;
    float s = 0.f, q = 0.f;
#pragma unroll 4
    for (int rr = 0; rr < 32; ++rr) {
        const float* src = (rr < 16)
            ? (s1 + ((i * 16 + rr) << 10))
            : (s2 + (((rr - 16) * 16 + i) << 10));
        f32x4 v = *(const f32x4*)(src + t * 4);
        s += v[0] + v[1] + v[2] + v[3];
        q += v[0]*v[0] + v[1]*v[1] + v[2]*v[2] + v[3]*v[3];
        if ((t >> 5) == cb)
            *(f32x4*)(a_buf + ((i * 32 + rr) << 10) + t * 4) = v;
    }
    reduce256(s, q, t, lds);
    float mean = s * (1.f / NELEM);
    float var = q * (1.f / NELEM) - mean * mean;
    float inv = rsqrtf(var + EPSLN);
    int c = cb * 128 + (t & 31) * 4;
    int r0 = (t >> 5) * 4;
#pragma unroll
    for (int rr = 0; rr < 4; ++rr) {
        int row = r0 + rr;
        const float* src = (row < 16)
            ? (s1 + ((i * 16 + row) << 10))
            : (s2 + (((row - 16) * 16 + i) << 10));
        f32x4 v = *(const f32x4*)(src + c);
        int base = ((i * 32 + row) << 10) + c;
        f32x4 gwv = *(const f32x4*)(gw + base);
        f32x4 gbv = *(const f32x4*)(gb + base);
        f32x4 hwv = *(const f32x4*)(hw + base);
        f32x4 hbv = *(const f32x4*)(hb + base);
        float z0 = (v[0]-mean)*inv, z1 = (v[1]-mean)*inv, z2 = (v[2]-mean)*inv, z3 = (v[3]-mean)*inv;
        uint2 a, b;
        a.x = (unsigned)f2bf(z0*gwv[0]+gbv[0]) | ((unsigned)f2bf(z1*gwv[1]+gbv[1]) << 16);
        a.y = (unsigned)f2bf(z2*gwv[2]+gbv[2]) | ((unsigned)f2bf(z3*gwv[3]+gbv[3]) << 16);
        b.x = (unsigned)f2bf(z0*hwv[0]+hbv[0]) | ((unsigned)f2bf(z1*hwv[1]+hbv[1]) << 16);
        b.y = (unsigned)f2bf(z2*hwv[2]+hbv[2]) | ((unsigned)f2bf(z3*hwv[3]+hbv[3]) << 16);
        *(uint2*)(xn + base) = a;
        *(uint2*)(yn + base) = b;
    }
}

// ---- LN2: stats over x1 (redundant per block), apply lf -> lnf ------------
__global__ void k_ln2(const float* __restrict__ x1,
                      const float* __restrict__ gw, const float* __restrict__ gb,
                      u16* __restrict__ out) {
    __shared__ float lds[10];
    int i = blockIdx.x, cb = blockIdx.y, t = threadIdx.x;
    float s = 0.f, q = 0.f;
#pragma unroll 4
    for (int rr = 0; rr < 32; ++rr) {
        f32x4 v = *(const f32x4*)(x1 + ((i * 32 + rr) << 10) + t * 4);
        s += v[0] + v[1] + v[2] + v[3];
        q += v[0]*v[0] + v[1]*v[1] + v[2]*v[2] + v[3]*v[3];
    }
    reduce256(s, q, t, lds);
    float mean = s * (1.f / NELEM);
    float var = q * (1.f / NELEM) - mean * mean;
    float inv = rsqrtf(var + EPSLN);
    int c = cb * 128 + (t & 31) * 4;
    int r0 = (t >> 5) * 4;
#pragma unroll
    for (int rr = 0; rr < 4; ++rr) {
        int base = ((i * 32 + r0 + rr) << 10) + c;
        f32x4 v  = *(const f32x4*)(x1 + base);
        f32x4 gwv = *(const f32x4*)(gw + base);
        f32x4 gbv = *(const f32x4*)(gb + base);
        float z0 = (v[0]-mean)*inv, z1 = (v[1]-mean)*inv, z2 = (v[2]-mean)*inv, z3 = (v[3]-mean)*inv;
        uint2 a;
        a.x = (unsigned)f2bf(z0*gwv[0]+gbv[0]) | ((unsigned)f2bf(z1*gwv[1]+gbv[1]) << 16);
        a.y = (unsigned)f2bf(z2*gwv[2]+gbv[2]) | ((unsigned)f2bf(z3*gwv[3]+gbv[3]) << 16);
        *(uint2*)(out + base) = a;
    }
}

// ---- QKV GEMM (swizzled chunks), in-block split-K2: 512 thr ---------------
__global__ void __launch_bounds__(512, 4)
k_gemm_qkv(const u16* __restrict__ xn, const u16* __restrict__ yn,
           const u16* __restrict__ wq, const float* __restrict__ wqb,
           const u16* __restrict__ wk, const float* __restrict__ wkb,
           const u16* __restrict__ wv, const float* __restrict__ wvb,
           u16* __restrict__ qo, u16* __restrict__ ko, u16* __restrict__ vT) {
    __shared__ float Pl[2][32][64];
    int bx = blockIdx.x, i = blockIdx.y;
    int w = threadIdx.x >> 6, lane = threadIdx.x & 63;
    int kh = w >> 2, mh = (w >> 1) & 1, wn = w & 1;
    int lr = lane & 15, kg = lane >> 4;
    int sel = bx >> 3;
    int ntl = (bx - sel * 8) * 2 + wn;
    const u16* act = (sel == 0 ? xn : yn) + (i * 32 + mh * 16 + lr) * C1024 + kh * 512 + kg * 8;
    const u16* Wm = (sel == 0 ? wq : (sel == 1 ? wk : wv));
    const u16* p = Wm + (((size_t)i * 16 + ntl) * 32 + kh * 16) * 1024 + lane * 8;
    f32x4 a0 = {0.f, 0.f, 0.f, 0.f}, a1 = {0.f, 0.f, 0.f, 0.f};
    mmz(act, p, 16, a0, a1);
    int m0 = mh * 16 + kg * 4;
#pragma unroll
    for (int r = 0; r < 4; ++r) {
        Pl[kh][m0 + r][wn * 32 + lr] = a0[r];
        Pl[kh][m0 + r][wn * 32 + 16 + lr] = a1[r];
    }
    __syncthreads();
    int t = threadIdx.x;
    int row = t >> 4, c0 = (t & 15) * 4;
    int nloc = bx * 64 - sel * 512 + c0;
    const float* bias = (sel == 0 ? wqb : (sel == 1 ? wkb : wvb)) + i * D512 + nloc;
    float v0 = Pl[0][row][c0]     + Pl[1][row][c0]     + bias[0];
    float v1 = Pl[0][row][c0 + 1] + Pl[1][row][c0 + 1] + bias[1];
    float v2 = Pl[0][row][c0 + 2] + Pl[1][row][c0 + 2] + bias[2];
    float v3 = Pl[0][row][c0 + 3] + Pl[1][row][c0 + 3] + bias[3];
    if (sel == 0) {
        uint2 a;
        a.x = (unsigned)f2bf(v0 * QSCALE) | ((unsigned)f2bf(v1 * QSCALE) << 16);
        a.y = (unsigned)f2bf(v2 * QSCALE) | ((unsigned)f2bf(v3 * QSCALE) << 16);
        *(uint2*)(qo + (i * 32 + row) * D512 + nloc) = a;
    } else if (sel == 1) {
        uint2 a;
        a.x = (unsigned)f2bf(v0) | ((unsigned)f2bf(v1) << 16);
        a.y = (unsigned)f2bf(v2) | ((unsigned)f2bf(v3) << 16);
        *(uint2*)(ko + (i * 32 + row) * D512 + nloc) = a;
    } else {
        int h = nloc >> 5, d = nloc & 31;
        u16* vb = vT + ((i * 16 + h) * 32 + d) * 32 + row;
        vb[0]  = f2bf(v0);
        vb[32] = f2bf(v1);
        vb[64] = f2bf(v2);
        vb[96] = f2bf(v3);
    }
}

// ---- attention per (idx, head) --------------------------------------------
__global__ void k_attn(const u16* __restrict__ q, const u16* __restrict__ k,
                       const u16* __restrict__ vT, u16* __restrict__ o) {
    __shared__ __align__(16) u16 Sm[4][32][32];
    int i = blockIdx.x;
    int w = threadIdx.x >> 6, lane = threadIdx.x & 63;
    int h = blockIdx.y * 4 + w;
    int lr = lane & 15, kg = lane >> 4;
    const u16* qb = q + i * 32 * D512 + h * 32 + kg * 8;
    const u16* kb = k + i * 32 * D512 + h * 32 + kg * 8;
    bf16x8 a0 = *(const bf16x8*)(qb + lr * D512);
    bf16x8 a1 = *(const bf16x8*)(qb + (16 + lr) * D512);
    bf16x8 b0 = *(const bf16x8*)(kb + lr * D512);
    bf16x8 b1 = *(const bf16x8*)(kb + (16 + lr) * D512);
    f32x4 z = {0.f, 0.f, 0.f, 0.f};
    f32x4 s00 = __builtin_amdgcn_mfma_f32_16x16x32_bf16(a0, b0, z, 0, 0, 0);
    f32x4 s01 = __builtin_amdgcn_mfma_f32_16x16x32_bf16(a0, b1, z, 0, 0, 0);
    f32x4 s10 = __builtin_amdgcn_mfma_f32_16x16x32_bf16(a1, b0, z, 0, 0, 0);
    f32x4 s11 = __builtin_amdgcn_mfma_f32_16x16x32_bf16(a1, b1, z, 0, 0, 0);
    int mr = kg * 4;
#pragma unroll
    for (int r = 0; r < 4; ++r) {
        Sm[w][mr + r][lr]           = f2bf(s00[r]);
        Sm[w][mr + r][16 + lr]      = f2bf(s01[r]);
        Sm[w][16 + mr + r][lr]      = f2bf(s10[r]);
        Sm[w][16 + mr + r][16 + lr] = f2bf(s11[r]);
    }
    __syncthreads();
    bf16x8 p0 = *(const bf16x8*)&Sm[w][lr][kg * 8];
    bf16x8 p1 = *(const bf16x8*)&Sm[w][16 + lr][kg * 8];
    const u16* vb = vT + (i * 16 + h) * 32 * 32 + kg * 8;
    bf16x8 v0 = *(const bf16x8*)(vb + lr * 32);
    bf16x8 v1 = *(const bf16x8*)(vb + (16 + lr) * 32);
    f32x4 o00 = __builtin_amdgcn_mfma_f32_16x16x32_bf16(p0, v0, z, 0, 0, 0);
    f32x4 o01 = __builtin_amdgcn_mfma_f32_16x16x32_bf16(p0, v1, z, 0, 0, 0);
    f32x4 o10 = __builtin_amdgcn_mfma_f32_16x16x32_bf16(p1, v0, z, 0, 0, 0);
    f32x4 o11 = __builtin_amdgcn_mfma_f32_16x16x32_bf16(p1, v1, z, 0, 0, 0);
#pragma unroll
    for (int r = 0; r < 4; ++r) {
        o[(i * 32 + mr + r) * D512 + h * 32 + lr]           = f2bf(o00[r]);
        o[(i * 32 + mr + r) * D512 + h * 32 + 16 + lr]      = f2bf(o01[r]);
        o[(i * 32 + 16 + mr + r) * D512 + h * 32 + lr]      = f2bf(o10[r]);
        o[(i * 32 + 16 + mr + r) * D512 + h * 32 + 16 + lr] = f2bf(o11[r]);
    }
}

// ---- w1 GEMM (swizzled chunks), in-block split-K2: 512 thr ----------------
__global__ void __launch_bounds__(512, 4)
k_gemm_w1(const u16* __restrict__ ob, const u16* __restrict__ W,
          const float* __restrict__ bias, const float* __restrict__ a_buf,
          float* __restrict__ x1) {
    __shared__ float Pl[2][32][64];
    int bx = blockIdx.x, i = blockIdx.y;
    int w = threadIdx.x >> 6, lane = threadIdx.x & 63;
    int kh = w >> 2, mh = (w >> 1) & 1, wn = w & 1;
    int lr = lane & 15, kg = lane >> 4;
    int nt = bx * 2 + wn;
    const u16* act = ob + (i * 32 + mh * 16 + lr) * D512 + kh * 256 + kg * 8;
    const u16* p = W + (((size_t)i * 32 + nt) * 16 + kh * 8) * 1024 + lane * 8;
    f32x4 a0 = {0.f, 0.f, 0.f, 0.f}, a1 = {0.f, 0.f, 0.f, 0.f};
    mmz(act, p, 8, a0, a1);
    int m0 = mh * 16 + kg * 4;
#pragma unroll
    for (int r = 0; r < 4; ++r) {
        Pl[kh][m0 + r][wn * 32 + lr] = a0[r];
        Pl[kh][m0 + r][wn * 32 + 16 + lr] = a1[r];
    }
    __syncthreads();
    int t = threadIdx.x;
    int row = t >> 4, c0 = (t & 15) * 4;
    int n = bx * 64 + c0;
    int base = ((i * 32 + row) << 10) + n;
    f32x4 bv = *(const f32x4*)(bias + i * C1024 + n);
    f32x4 av = *(const f32x4*)(a_buf + base);
    f32x4 r;
    r[0] = Pl[0][row][c0]     + Pl[1][row][c0]     + bv[0] + av[0];
    r[1] = Pl[0][row][c0 + 1] + Pl[1][row][c0 + 1] + bv[1] + av[1];
    r[2] = Pl[0][row][c0 + 2] + Pl[1][row][c0 + 2] + bv[2] + av[2];
    r[3] = Pl[0][row][c0 + 3] + Pl[1][row][c0 + 3] + bv[3] + av[3];
    *(f32x4*)(x1 + base) = r;
}

// ---- w2 GEMM (swizzled chunks): 256 thr; bxoff for half-launches ----------
__global__ void __launch_bounds__(256, 4)
k_gemm_w2(const u16* __restrict__ lnf, const u16* __restrict__ W,
          const float* __restrict__ bias, u16* __restrict__ hb, int bxoff) {
    int bx = blockIdx.x + bxoff, i = blockIdx.y;
    int w = threadIdx.x >> 6, lane = threadIdx.x & 63;
    int mh = w & 1, wn = w >> 1, lr = lane & 15, kg = lane >> 4;
    int nt = bx * 2 + wn;
    const u16* act = lnf + (i * 32 + mh * 16 + lr) * C1024 + kg * 8;
    const u16* p = W + (((size_t)i * 128 + nt) * 32) * 1024 + lane * 8;
    f32x4 a0 = {0.f, 0.f, 0.f, 0.f}, a1 = {0.f, 0.f, 0.f, 0.f};
    mmz(act, p, 32, a0, a1);
    int m0 = mh * 16 + kg * 4;
    int nb = bx * 64 + wn * 32;
    int n0 = nb + lr, n1 = nb + 16 + lr;
    float b0 = bias[i * FF4096 + n0], b1 = bias[i * FF4096 + n1];
#pragma unroll
    for (int r = 0; r < 4; ++r) {
        float t0 = a0[r] + b0;
        float t1 = a1[r] + b1;
        float g0 = 0.5f * t0 * (1.f + erff(t0 * 0.70710678118654752f));
        float g1 = 0.5f * t1 * (1.f + erff(t1 * 0.70710678118654752f));
        hb[(i * 32 + m0 + r) * FF4096 + n0] = f2bf(g0);
        hb[(i * 32 + m0 + r) * FF4096 + n1] = f2bf(g1);
    }
}

// ---- w3 GEMM (swizzled chunks), in-block split-K4: 1024 thr ---------------
__global__ void __launch_bounds__(1024, 4)
k_gemm_w3(const u16* __restrict__ hb, const u16* __restrict__ W,
          const float* __restrict__ bias, const float* __restrict__ x1,
          float* __restrict__ xout, int m1, int m2, int bxoff) {
    __shared__ float Pl[4][32][64];
    int bx = blockIdx.x + bxoff, i = blockIdx.y;
    int w = threadIdx.x >> 6, lane = threadIdx.x & 63;
    int kq = w >> 2, mh = (w >> 1) & 1, wn = w & 1;
    int lr = lane & 15, kg = lane >> 4;
    int nt = bx * 2 + wn;
    const u16* act = hb + (i * 32 + mh * 16 + lr) * FF4096 + kq * 1024 + kg * 8;
    const u16* p = W + (((size_t)i * 32 + nt) * 128 + kq * 32) * 1024 + lane * 8;
    f32x4 a0 = {0.f, 0.f, 0.f, 0.f}, a1 = {0.f, 0.f, 0.f, 0.f};
    mmz(act, p, 32, a0, a1);
    int m0 = mh * 16 + kg * 4;
#pragma unroll
    for (int r = 0; r < 4; ++r) {
        Pl[kq][m0 + r][wn * 32 + lr] = a0[r];
        Pl[kq][m0 + r][wn * 32 + 16 + lr] = a1[r];
    }
    __syncthreads();
    int t = threadIdx.x;
    int row = t >> 5, c0 = (t & 31) * 2;
    int n = bx * 64 + c0;
    int dst = (row < 16) ? (((m1 * 16 + i) * 16 + row) << 10)
                         : (((m2 * 16 + i) * 16 + (row - 16)) << 10);
    int base = ((i * 32 + row) << 10) + n;
#pragma unroll
    for (int j = 0; j < 2; ++j) {
        float v = Pl[0][row][c0 + j] + Pl[1][row][c0 + j]
                + Pl[2][row][c0 + j] + Pl[3][row][c0 + j]
                + bias[i * C1024 + n + j] + x1[base + j];
        xout[dst + n + j] = v;
    }
}

// ---------------------------------------------------------------------------
extern "C" void kernel_launch(void* const* d_in, const int* in_sizes, int n_in,
                              void* d_out, int out_size, void* d_ws, size_t ws_size,
                              hipStream_t stream) {
    const float* x_in = (const float*)d_in[0];
    const float* lx_w = (const float*)d_in[1];
    const float* lx_b = (const float*)d_in[2];
    const float* ly_w = (const float*)d_in[3];
    const float* ly_b = (const float*)d_in[4];
    const float* lf_w = (const float*)d_in[5];
    const float* lf_b = (const float*)d_in[6];
    const float* wq_w = (const float*)d_in[7];
    const float* wq_b = (const float*)d_in[8];
    const float* wk_w = (const float*)d_in[9];
    const float* wk_b = (const float*)d_in[10];
    const float* wv_w = (const float*)d_in[11];
    const float* wv_b = (const float*)d_in[12];
    const float* w1   = (const float*)d_in[13];
    const float* b1   = (const float*)d_in[14];
    const float* w2   = (const float*)d_in[15];
    const float* b2   = (const float*)d_in[16];
    const float* w3   = (const float*)d_in[17];
    const float* b3   = (const float*)d_in[18];

    float* xbuf = (float*)d_out;   // working state x [3][16][16][1024]
    char* ws = (char*)d_ws;
    float* a_buf  = (float*)(ws);                          //  2 MB @ 0
    float* x1_buf = (float*)(ws + (2u << 20));             //  2 MB @ 2
    u16*   xn     = (u16*)(ws + (4u << 20));               //  1 MB @ 4
    u16*   yn     = (u16*)(ws + (5u << 20));               //  1 MB @ 5
    u16*   lnf    = (u16*)(ws + (6u << 20));               //  1 MB @ 6
    u16*   qb     = (u16*)(ws + (7u << 20));               // .5 MB @ 7
    u16*   kb     = (u16*)(ws + 7 * (1u << 20) + (1u << 19));
    u16*   vT     = (u16*)(ws + (8u << 20));               // .5 MB @ 8
    u16*   ob     = (u16*)(ws + 8 * (1u << 20) + (1u << 19));
    u16*   hbuf   = (u16*)(ws + (9u << 20));               //  4 MB @ 9
    u16*   wq16   = (u16*)(ws + (16u  << 20));             // 16 MB @ 16
    u16*   wk16   = (u16*)(ws + (32u  << 20));             // 16 MB @ 32
    u16*   wv16   = (u16*)(ws + (48u  << 20));             // 16 MB @ 48
    u16*   w1_16  = (u16*)(ws + (64u  << 20));             // 16 MB @ 64
    u16*   w2_16  = (u16*)(ws + (80u  << 20));             // 128 MB @ 80
    u16*   w3_16  = (u16*)(ws + (208u << 20));             // 128 MB @ 208

    const size_t SLAB = (size_t)16 * 16 * 1024;
    const int modes[3][2] = {{0, 1}, {2, 0}, {1, 2}};
    for (int mi = 0; mi < 3; ++mi) {
        int m1 = modes[mi][0], m2 = modes[mi][1];
        const float* s1 = (mi == 2) ? (xbuf + m1 * SLAB) : (x_in + m1 * SLAB);
        const float* s2 = (mi == 0) ? (x_in + m2 * SLAB) : (xbuf + m2 * SLAB);
        if (mi == 0) {
            // convert qkv + w1 weights just before their consumers (L3-hot)
            k_cvt<<<1024, 256, 0, stream>>>(wq_w, wq16, 16, 4, 0, 16);
            k_cvt<<<1024, 256, 0, stream>>>(wk_w, wk16, 16, 4, 0, 16);
            k_cvt<<<1024, 256, 0, stream>>>(wv_w, wv16, 16, 4, 0, 16);
            k_cvt<<<1024, 256, 0, stream>>>(w1,   w1_16, 32, 2, 0, 32);
        }
        k_ln1<<<dim3(16, 8), 256, 0, stream>>>(s1, s2, lx_w, lx_b, ly_w, ly_b, a_buf, xn, yn);
        k_gemm_qkv<<<dim3(24, 16), 512, 0, stream>>>(xn, yn, wq16, wq_b, wk16, wk_b, wv16, wv_b, qb, kb, vT);
        k_attn<<<dim3(16, 4), 256, 0, stream>>>(qb, kb, vT, ob);
        k_gemm_w1<<<dim3(16, 16), 512, 0, stream>>>(ob, w1_16, b1, a_buf, x1_buf);
        k_ln2<<<dim3(16, 8), 256, 0, stream>>>(x1_buf, lf_w, lf_b, lnf);
        if (mi == 0) {
            // w2/w3: cvt-half immediately before gemm-half (201MB phase < L3)
            k_cvt<<<4096, 256, 0, stream>>>(w2, w2_16, 128, 4, 0, 64);
            k_gemm_w2<<<dim3(32, 16), 256, 0, stream>>>(lnf, w2_16, b2, hbuf, 0);
            k_cvt<<<4096, 256, 0, stream>>>(w2, w2_16, 128, 4, 64, 64);
            k_gemm_w2<<<dim3(32, 16), 256, 0, stream>>>(lnf, w2_16, b2, hbuf, 32);
            k_cvt<<<4096, 256, 0, stream>>>(w3, w3_16, 32, 16, 0, 16);
            k_gemm_w3<<<dim3(8, 16), 1024, 0, stream>>>(hbuf, w3_16, b3, x1_buf, xbuf, m1, m2, 0);
            k_cvt<<<4096, 256, 0, stream>>>(w3, w3_16, 32, 16, 16, 16);
            k_gemm_w3<<<dim3(8, 16), 1024, 0, stream>>>(hbuf, w3_16, b3, x1_buf, xbuf, m1, m2, 8);
        } else {
            k_gemm_w2<<<dim3(64, 16), 256, 0, stream>>>(lnf, w2_16, b2, hbuf, 0);
            k_gemm_w3<<<dim3(16, 16), 1024, 0, stream>>>(hbuf, w3_16, b3, x1_buf, xbuf, m1, m2, 0);
        }
    }
}

// Round 3
// 536.465 us; speedup vs baseline: 1.0784x; 1.0483x over previous
//
#include <hip/hip_runtime.h>

// ---------------------------------------------------------------------------
// AttentiveModes (S=16, C=1024, H=16, DH=32) on MI355X.
// Round 15: revert to R12 structure (single unified cvt before everything,
// best measured 537-538us). One change: cvt tile halved to 16 rows x 256 k
// (LDS 16.5KB, __launch_bounds__(256,8)) -> 8 blocks/CU instead of <4.
// cvt was 34% occupancy / 5.0 TB/s demand; more resident blocks = more loads
// in flight. Phase-1 segments grow to 256B (16-lane groups); phase-2 wave
// writes remain 1KB contiguous (one 512-elem b-half per wave pass).
// ---------------------------------------------------------------------------

#define C1024 1024
#define D512  512
#define FF4096 4096
#define NELEM 32768.0f
#define EPSLN 1e-5f
#define QSCALE 0.17677669529663687f  // 1/sqrt(32)
#define LP 258                        // LDS pitch in f32 words

typedef __attribute__((ext_vector_type(8))) short bf16x8;
typedef __attribute__((ext_vector_type(4))) float f32x4;
typedef unsigned short u16;

__device__ inline u16 f2bf(float f) {
    unsigned u = __float_as_uint(f);
    u += 0x7fffu + ((u >> 16) & 1u);
    return (u16)(u >> 16);
}

__device__ inline bf16x8 cvt8(f32x4 a, f32x4 b) {
    bf16x8 r;
    r[0] = (short)f2bf(a[0]); r[1] = (short)f2bf(a[1]);
    r[2] = (short)f2bf(a[2]); r[3] = (short)f2bf(a[3]);
    r[4] = (short)f2bf(b[0]); r[5] = (short)f2bf(b[1]);
    r[6] = (short)f2bf(b[2]); r[7] = (short)f2bf(b[3]);
    return r;
}

// ---- cvt v7: 16-row tiles, 8 blocks/CU ------------------------------------
// Tile = (i,nt,b,kz): 16 rows x 256 k fp32 (rows b*16..b*16+15 of the 32-row
// n-tile). Phase 1: thread (row=t>>4, c16=t&15) loads f32x4 at col c16*4+64j
// (16-lane row-groups = 256B contiguous segments). Phase 2: u = p*2048+t*8,
// decode (c,kg,lr); read 8 f32 from LDS; write bf16x8 at chunk offset
// c*1024 + b*512 + kg*128 + lr*8 -> each wave pass = 1KB contiguous.
struct Cvt6 {
    const float* s[6];
    u16* d[6];
    int N32[6], kzs[6], base[6];
};
__global__ void __launch_bounds__(256, 8) k_cvt6(Cvt6 a) {
    __shared__ float lds[16 * LP];    // 16.5 KB
    int bid = blockIdx.x;
    int ts = 0;
#pragma unroll
    for (int j = 1; j < 6; ++j) if (bid >= a.base[j]) ts = j;
    int local = bid - a.base[ts];
    int kzs = a.kzs[ts], N32 = a.N32[ts];
    int kz = local % kzs;
    int b  = (local / kzs) & 1;
    int nt = (local / (kzs * 2)) % N32;
    int i  = local / (kzs * 2 * N32);
    int K = kzs * 256;
    int t = threadIdx.x;
    // phase 1: contiguous wave reads (256B per 16-lane row-group)
    int row = t >> 4, c16 = t & 15;
    const float* Sp = a.s[ts] + ((size_t)((i * N32 + nt) * 32) + b * 16 + row) * K + kz * 256 + c16 * 4;
    float* Lrow = lds + row * LP + c16 * 4;
#pragma unroll
    for (int j = 0; j < 4; ++j) {
        f32x4 v = *(const f32x4*)(Sp + 64 * j);
        Lrow[64 * j]     = v[0];
        Lrow[64 * j + 1] = v[1];
        Lrow[64 * j + 2] = v[2];
        Lrow[64 * j + 3] = v[3];
    }
    __syncthreads();
    // phase 2: chunk-ordered conversion + linear global writes
    u16* Dp = a.d[ts] + (((size_t)(i * N32 + nt) * (kzs * 8) + kz * 8) * 1024) + b * 512;
#pragma unroll
    for (int p = 0; p < 2; ++p) {
        int u = p * 2048 + t * 8;
        int c   = u >> 9;
        int rem = u & 511;
        int kg = rem >> 7;
        int lr = (rem >> 3) & 15;
        const float* src = lds + lr * LP + c * 32 + kg * 8;
        f32x4 lo, hi;
        lo[0] = src[0]; lo[1] = src[1]; lo[2] = src[2]; lo[3] = src[3];
        hi[0] = src[4]; hi[1] = src[5]; hi[2] = src[6]; hi[3] = src[7];
        *(bf16x8*)(Dp + c * 1024 + rem) = cvt8(lo, hi);
    }
}

// swizzled-weight inner loop: p pre-offset by lane*8; 1KB/frag contiguous.
__device__ inline void mmz(const u16* __restrict__ act, const u16* __restrict__ p,
                           int nkk, f32x4& acc0, f32x4& acc1) {
#pragma unroll 4
    for (int j = 0; j < nkk; ++j) {
        bf16x8 aF = *(const bf16x8*)(act + j * 32);
        bf16x8 b0 = *(const bf16x8*)(p + (size_t)j * 1024);
        bf16x8 b1 = *(const bf16x8*)(p + (size_t)j * 1024 + 512);
        acc0 = __builtin_amdgcn_mfma_f32_16x16x32_bf16(aF, b0, acc0, 0, 0, 0);
        acc1 = __builtin_amdgcn_mfma_f32_16x16x32_bf16(aF, b1, acc1, 0, 0, 0);
    }
}

// 256-thread block reduce of (s,q); lds >= 10 floats.
__device__ inline void reduce256(float& s, float& q, int t, float* lds) {
    for (int off = 32; off; off >>= 1) {
        s += __shfl_down(s, off, 64);
        q += __shfl_down(q, off, 64);
    }
    int wv = t >> 6;
    if ((t & 63) == 0) { lds[wv * 2] = s; lds[wv * 2 + 1] = q; }
    __syncthreads();
    if (t == 0) {
        lds[8] = lds[0] + lds[2] + lds[4] + lds[6];
        lds[9] = lds[1] + lds[3] + lds[5] + lds[7];
    }
    __syncthreads();
    s = lds[8]; q = lds[9];
}

// ---- LN1: gather from two slab bases, redundant stats, apply lx/ly --------
__global__ void k_ln1(const float* __restrict__ s1, const float* __restrict__ s2,
                      const float* __restrict__ gw, const float* __restrict__ gb,
                      const float* __restrict__ hw, const float* __restrict__ hb,
                      float* __restrict__ a_buf,
                      u16* __restrict__ xn, u16* __restrict__ yn) {
    __shared__ float lds[10];
    int i = blockIdx.x, cb = blockIdx.y, t = threadIdx.x;
    float s = 0.f, q = 0.f;
#pragma unroll 4
    for (int rr = 0; rr < 32; ++rr) {
        const float* src = (rr < 16)
            ? (s1 + ((i * 16 + rr) << 10))
            : (s2 + (((rr - 16) * 16 + i) << 10));
        f32x4 v = *(const f32x4*)(src + t * 4);
        s += v[0] + v[1] + v[2] + v[3];
        q += v[0]*v[0] + v[1]*v[1] + v[2]*v[2] + v[3]*v[3];
        if ((t >> 5) == cb)
            *(f32x4*)(a_buf + ((i * 32 + rr) << 10) + t * 4) = v;
    }
    reduce256(s, q, t, lds);
    float mean = s * (1.f / NELEM);
    float var = q * (1.f / NELEM) - mean * mean;
    float inv = rsqrtf(var + EPSLN);
    int c = cb * 128 + (t & 31) * 4;
    int r0 = (t >> 5) * 4;
#pragma unroll
    for (int rr = 0; rr < 4; ++rr) {
        int row = r0 + rr;
        const float* src = (row < 16)
            ? (s1 + ((i * 16 + row) << 10))
            : (s2 + (((row - 16) * 16 + i) << 10));
        f32x4 v = *(const f32x4*)(src + c);
        int base = ((i * 32 + row) << 10) + c;
        f32x4 gwv = *(const f32x4*)(gw + base);
        f32x4 gbv = *(const f32x4*)(gb + base);
        f32x4 hwv = *(const f32x4*)(hw + base);
        f32x4 hbv = *(const f32x4*)(hb + base);
        float z0 = (v[0]-mean)*inv, z1 = (v[1]-mean)*inv, z2 = (v[2]-mean)*inv, z3 = (v[3]-mean)*inv;
        uint2 a, b;
        a.x = (unsigned)f2bf(z0*gwv[0]+gbv[0]) | ((unsigned)f2bf(z1*gwv[1]+gbv[1]) << 16);
        a.y = (unsigned)f2bf(z2*gwv[2]+gbv[2]) | ((unsigned)f2bf(z3*gwv[3]+gbv[3]) << 16);
        b.x = (unsigned)f2bf(z0*hwv[0]+hbv[0]) | ((unsigned)f2bf(z1*hwv[1]+hbv[1]) << 16);
        b.y = (unsigned)f2bf(z2*hwv[2]+hbv[2]) | ((unsigned)f2bf(z3*hwv[3]+hbv[3]) << 16);
        *(uint2*)(xn + base) = a;
        *(uint2*)(yn + base) = b;
    }
}

// ---- LN2: stats over x1 (redundant per block), apply lf -> lnf ------------
__global__ void k_ln2(const float* __restrict__ x1,
                      const float* __restrict__ gw, const float* __restrict__ gb,
                      u16* __restrict__ out) {
    __shared__ float lds[10];
    int i = blockIdx.x, cb = blockIdx.y, t = threadIdx.x;
    float s = 0.f, q = 0.f;
#pragma unroll 4
    for (int rr = 0; rr < 32; ++rr) {
        f32x4 v = *(const f32x4*)(x1 + ((i * 32 + rr) << 10) + t * 4);
        s += v[0] + v[1] + v[2] + v[3];
        q += v[0]*v[0] + v[1]*v[1] + v[2]*v[2] + v[3]*v[3];
    }
    reduce256(s, q, t, lds);
    float mean = s * (1.f / NELEM);
    float var = q * (1.f / NELEM) - mean * mean;
    float inv = rsqrtf(var + EPSLN);
    int c = cb * 128 + (t & 31) * 4;
    int r0 = (t >> 5) * 4;
#pragma unroll
    for (int rr = 0; rr < 4; ++rr) {
        int base = ((i * 32 + r0 + rr) << 10) + c;
        f32x4 v  = *(const f32x4*)(x1 + base);
        f32x4 gwv = *(const f32x4*)(gw + base);
        f32x4 gbv = *(const f32x4*)(gb + base);
        float z0 = (v[0]-mean)*inv, z1 = (v[1]-mean)*inv, z2 = (v[2]-mean)*inv, z3 = (v[3]-mean)*inv;
        uint2 a;
        a.x = (unsigned)f2bf(z0*gwv[0]+gbv[0]) | ((unsigned)f2bf(z1*gwv[1]+gbv[1]) << 16);
        a.y = (unsigned)f2bf(z2*gwv[2]+gbv[2]) | ((unsigned)f2bf(z3*gwv[3]+gbv[3]) << 16);
        *(uint2*)(out + base) = a;
    }
}

// ---- QKV GEMM (swizzled chunks), in-block split-K2: 512 thr ---------------
__global__ void __launch_bounds__(512, 4)
k_gemm_qkv(const u16* __restrict__ xn, const u16* __restrict__ yn,
           const u16* __restrict__ wq, const float* __restrict__ wqb,
           const u16* __restrict__ wk, const float* __restrict__ wkb,
           const u16* __restrict__ wv, const float* __restrict__ wvb,
           u16* __restrict__ qo, u16* __restrict__ ko, u16* __restrict__ vT) {
    __shared__ float Pl[2][32][64];
    int bx = blockIdx.x, i = blockIdx.y;
    int w = threadIdx.x >> 6, lane = threadIdx.x & 63;
    int kh = w >> 2, mh = (w >> 1) & 1, wn = w & 1;
    int lr = lane & 15, kg = lane >> 4;
    int sel = bx >> 3;
    int ntl = (bx - sel * 8) * 2 + wn;
    const u16* act = (sel == 0 ? xn : yn) + (i * 32 + mh * 16 + lr) * C1024 + kh * 512 + kg * 8;
    const u16* Wm = (sel == 0 ? wq : (sel == 1 ? wk : wv));
    const u16* p = Wm + (((size_t)i * 16 + ntl) * 32 + kh * 16) * 1024 + lane * 8;
    f32x4 a0 = {0.f, 0.f, 0.f, 0.f}, a1 = {0.f, 0.f, 0.f, 0.f};
    mmz(act, p, 16, a0, a1);
    int m0 = mh * 16 + kg * 4;
#pragma unroll
    for (int r = 0; r < 4; ++r) {
        Pl[kh][m0 + r][wn * 32 + lr] = a0[r];
        Pl[kh][m0 + r][wn * 32 + 16 + lr] = a1[r];
    }
    __syncthreads();
    int t = threadIdx.x;
    int row = t >> 4, c0 = (t & 15) * 4;
    int nloc = bx * 64 - sel * 512 + c0;
    const float* bias = (sel == 0 ? wqb : (sel == 1 ? wkb : wvb)) + i * D512 + nloc;
    float v0 = Pl[0][row][c0]     + Pl[1][row][c0]     + bias[0];
    float v1 = Pl[0][row][c0 + 1] + Pl[1][row][c0 + 1] + bias[1];
    float v2 = Pl[0][row][c0 + 2] + Pl[1][row][c0 + 2] + bias[2];
    float v3 = Pl[0][row][c0 + 3] + Pl[1][row][c0 + 3] + bias[3];
    if (sel == 0) {
        uint2 a;
        a.x = (unsigned)f2bf(v0 * QSCALE) | ((unsigned)f2bf(v1 * QSCALE) << 16);
        a.y = (unsigned)f2bf(v2 * QSCALE) | ((unsigned)f2bf(v3 * QSCALE) << 16);
        *(uint2*)(qo + (i * 32 + row) * D512 + nloc) = a;
    } else if (sel == 1) {
        uint2 a;
        a.x = (unsigned)f2bf(v0) | ((unsigned)f2bf(v1) << 16);
        a.y = (unsigned)f2bf(v2) | ((unsigned)f2bf(v3) << 16);
        *(uint2*)(ko + (i * 32 + row) * D512 + nloc) = a;
    } else {
        int h = nloc >> 5, d = nloc & 31;
        u16* vb = vT + ((i * 16 + h) * 32 + d) * 32 + row;
        vb[0]  = f2bf(v0);
        vb[32] = f2bf(v1);
        vb[64] = f2bf(v2);
        vb[96] = f2bf(v3);
    }
}

// ---- attention per (idx, head) --------------------------------------------
__global__ void k_attn(const u16* __restrict__ q, const u16* __restrict__ k,
                       const u16* __restrict__ vT, u16* __restrict__ o) {
    __shared__ __align__(16) u16 Sm[4][32][32];
    int i = blockIdx.x;
    int w = threadIdx.x >> 6, lane = threadIdx.x & 63;
    int h = blockIdx.y * 4 + w;
    int lr = lane & 15, kg = lane >> 4;
    const u16* qb = q + i * 32 * D512 + h * 32 + kg * 8;
    const u16* kb = k + i * 32 * D512 + h * 32 + kg * 8;
    bf16x8 a0 = *(const bf16x8*)(qb + lr * D512);
    bf16x8 a1 = *(const bf16x8*)(qb + (16 + lr) * D512);
    bf16x8 b0 = *(const bf16x8*)(kb + lr * D512);
    bf16x8 b1 = *(const bf16x8*)(kb + (16 + lr) * D512);
    f32x4 z = {0.f, 0.f, 0.f, 0.f};
    f32x4 s00 = __builtin_amdgcn_mfma_f32_16x16x32_bf16(a0, b0, z, 0, 0, 0);
    f32x4 s01 = __builtin_amdgcn_mfma_f32_16x16x32_bf16(a0, b1, z, 0, 0, 0);
    f32x4 s10 = __builtin_amdgcn_mfma_f32_16x16x32_bf16(a1, b0, z, 0, 0, 0);
    f32x4 s11 = __builtin_amdgcn_mfma_f32_16x16x32_bf16(a1, b1, z, 0, 0, 0);
    int mr = kg * 4;
#pragma unroll
    for (int r = 0; r < 4; ++r) {
        Sm[w][mr + r][lr]           = f2bf(s00[r]);
        Sm[w][mr + r][16 + lr]      = f2bf(s01[r]);
        Sm[w][16 + mr + r][lr]      = f2bf(s10[r]);
        Sm[w][16 + mr + r][16 + lr] = f2bf(s11[r]);
    }
    __syncthreads();
    bf16x8 p0 = *(const bf16x8*)&Sm[w][lr][kg * 8];
    bf16x8 p1 = *(const bf16x8*)&Sm[w][16 + lr][kg * 8];
    const u16* vb = vT + (i * 16 + h) * 32 * 32 + kg * 8;
    bf16x8 v0 = *(const bf16x8*)(vb + lr * 32);
    bf16x8 v1 = *(const bf16x8*)(vb + (16 + lr) * 32);
    f32x4 o00 = __builtin_amdgcn_mfma_f32_16x16x32_bf16(p0, v0, z, 0, 0, 0);
    f32x4 o01 = __builtin_amdgcn_mfma_f32_16x16x32_bf16(p0, v1, z, 0, 0, 0);
    f32x4 o10 = __builtin_amdgcn_mfma_f32_16x16x32_bf16(p1, v0, z, 0, 0, 0);
    f32x4 o11 = __builtin_amdgcn_mfma_f32_16x16x32_bf16(p1, v1, z, 0, 0, 0);
#pragma unroll
    for (int r = 0; r < 4; ++r) {
        o[(i * 32 + mr + r) * D512 + h * 32 + lr]           = f2bf(o00[r]);
        o[(i * 32 + mr + r) * D512 + h * 32 + 16 + lr]      = f2bf(o01[r]);
        o[(i * 32 + 16 + mr + r) * D512 + h * 32 + lr]      = f2bf(o10[r]);
        o[(i * 32 + 16 + mr + r) * D512 + h * 32 + 16 + lr] = f2bf(o11[r]);
    }
}

// ---- w1 GEMM (swizzled chunks), in-block split-K2: 512 thr ----------------
__global__ void __launch_bounds__(512, 4)
k_gemm_w1(const u16* __restrict__ ob, const u16* __restrict__ W,
          const float* __restrict__ bias, const float* __restrict__ a_buf,
          float* __restrict__ x1) {
    __shared__ float Pl[2][32][64];
    int bx = blockIdx.x, i = blockIdx.y;
    int w = threadIdx.x >> 6, lane = threadIdx.x & 63;
    int kh = w >> 2, mh = (w >> 1) & 1, wn = w & 1;
    int lr = lane & 15, kg = lane >> 4;
    int nt = bx * 2 + wn;
    const u16* act = ob + (i * 32 + mh * 16 + lr) * D512 + kh * 256 + kg * 8;
    const u16* p = W + (((size_t)i * 32 + nt) * 16 + kh * 8) * 1024 + lane * 8;
    f32x4 a0 = {0.f, 0.f, 0.f, 0.f}, a1 = {0.f, 0.f, 0.f, 0.f};
    mmz(act, p, 8, a0, a1);
    int m0 = mh * 16 + kg * 4;
#pragma unroll
    for (int r = 0; r < 4; ++r) {
        Pl[kh][m0 + r][wn * 32 + lr] = a0[r];
        Pl[kh][m0 + r][wn * 32 + 16 + lr] = a1[r];
    }
    __syncthreads();
    int t = threadIdx.x;
    int row = t >> 4, c0 = (t & 15) * 4;
    int n = bx * 64 + c0;
    int base = ((i * 32 + row) << 10) + n;
    f32x4 bv = *(const f32x4*)(bias + i * C1024 + n);
    f32x4 av = *(const f32x4*)(a_buf + base);
    f32x4 r;
    r[0] = Pl[0][row][c0]     + Pl[1][row][c0]     + bv[0] + av[0];
    r[1] = Pl[0][row][c0 + 1] + Pl[1][row][c0 + 1] + bv[1] + av[1];
    r[2] = Pl[0][row][c0 + 2] + Pl[1][row][c0 + 2] + bv[2] + av[2];
    r[3] = Pl[0][row][c0 + 3] + Pl[1][row][c0 + 3] + bv[3] + av[3];
    *(f32x4*)(x1 + base) = r;
}

// ---- w2 GEMM (swizzled chunks): grid (64,16), 256 thr ---------------------
__global__ void __launch_bounds__(256, 4)
k_gemm_w2(const u16* __restrict__ lnf, const u16* __restrict__ W,
          const float* __restrict__ bias, u16* __restrict__ hb) {
    int bx = blockIdx.x, i = blockIdx.y;
    int w = threadIdx.x >> 6, lane = threadIdx.x & 63;
    int mh = w & 1, wn = w >> 1, lr = lane & 15, kg = lane >> 4;
    int nt = bx * 2 + wn;
    const u16* act = lnf + (i * 32 + mh * 16 + lr) * C1024 + kg * 8;
    const u16* p = W + (((size_t)i * 128 + nt) * 32) * 1024 + lane * 8;
    f32x4 a0 = {0.f, 0.f, 0.f, 0.f}, a1 = {0.f, 0.f, 0.f, 0.f};
    mmz(act, p, 32, a0, a1);
    int m0 = mh * 16 + kg * 4;
    int nb = bx * 64 + wn * 32;
    int n0 = nb + lr, n1 = nb + 16 + lr;
    float b0 = bias[i * FF4096 + n0], b1 = bias[i * FF4096 + n1];
#pragma unroll
    for (int r = 0; r < 4; ++r) {
        float t0 = a0[r] + b0;
        float t1 = a1[r] + b1;
        float g0 = 0.5f * t0 * (1.f + erff(t0 * 0.70710678118654752f));
        float g1 = 0.5f * t1 * (1.f + erff(t1 * 0.70710678118654752f));
        hb[(i * 32 + m0 + r) * FF4096 + n0] = f2bf(g0);
        hb[(i * 32 + m0 + r) * FF4096 + n1] = f2bf(g1);
    }
}

// ---- w3 GEMM (swizzled chunks), in-block split-K4: 1024 thr ---------------
__global__ void __launch_bounds__(1024, 4)
k_gemm_w3(const u16* __restrict__ hb, const u16* __restrict__ W,
          const float* __restrict__ bias, const float* __restrict__ x1,
          float* __restrict__ xout, int m1, int m2) {
    __shared__ float Pl[4][32][64];
    int bx = blockIdx.x, i = blockIdx.y;
    int w = threadIdx.x >> 6, lane = threadIdx.x & 63;
    int kq = w >> 2, mh = (w >> 1) & 1, wn = w & 1;
    int lr = lane & 15, kg = lane >> 4;
    int nt = bx * 2 + wn;
    const u16* act = hb + (i * 32 + mh * 16 + lr) * FF4096 + kq * 1024 + kg * 8;
    const u16* p = W + (((size_t)i * 32 + nt) * 128 + kq * 32) * 1024 + lane * 8;
    f32x4 a0 = {0.f, 0.f, 0.f, 0.f}, a1 = {0.f, 0.f, 0.f, 0.f};
    mmz(act, p, 32, a0, a1);
    int m0 = mh * 16 + kg * 4;
#pragma unroll
    for (int r = 0; r < 4; ++r) {
        Pl[kq][m0 + r][wn * 32 + lr] = a0[r];
        Pl[kq][m0 + r][wn * 32 + 16 + lr] = a1[r];
    }
    __syncthreads();
    int t = threadIdx.x;
    int row = t >> 5, c0 = (t & 31) * 2;
    int n = bx * 64 + c0;
    int dst = (row < 16) ? (((m1 * 16 + i) * 16 + row) << 10)
                         : (((m2 * 16 + i) * 16 + (row - 16)) << 10);
    int base = ((i * 32 + row) << 10) + n;
#pragma unroll
    for (int j = 0; j < 2; ++j) {
        float v = Pl[0][row][c0 + j] + Pl[1][row][c0 + j]
                + Pl[2][row][c0 + j] + Pl[3][row][c0 + j]
                + bias[i * C1024 + n + j] + x1[base + j];
        xout[dst + n + j] = v;
    }
}

// ---------------------------------------------------------------------------
extern "C" void kernel_launch(void* const* d_in, const int* in_sizes, int n_in,
                              void* d_out, int out_size, void* d_ws, size_t ws_size,
                              hipStream_t stream) {
    const float* x_in = (const float*)d_in[0];
    const float* lx_w = (const float*)d_in[1];
    const float* lx_b = (const float*)d_in[2];
    const float* ly_w = (const float*)d_in[3];
    const float* ly_b = (const float*)d_in[4];
    const float* lf_w = (const float*)d_in[5];
    const float* lf_b = (const float*)d_in[6];
    const float* wq_w = (const float*)d_in[7];
    const float* wq_b = (const float*)d_in[8];
    const float* wk_w = (const float*)d_in[9];
    const float* wk_b = (const float*)d_in[10];
    const float* wv_w = (const float*)d_in[11];
    const float* wv_b = (const float*)d_in[12];
    const float* w1   = (const float*)d_in[13];
    const float* b1   = (const float*)d_in[14];
    const float* w2   = (const float*)d_in[15];
    const float* b2   = (const float*)d_in[16];
    const float* w3   = (const float*)d_in[17];
    const float* b3   = (const float*)d_in[18];

    float* xbuf = (float*)d_out;   // working state x [3][16][16][1024]
    char* ws = (char*)d_ws;
    float* a_buf  = (float*)(ws);                          //  2 MB @ 0
    float* x1_buf = (float*)(ws + (2u << 20));             //  2 MB @ 2
    u16*   xn     = (u16*)(ws + (4u << 20));               //  1 MB @ 4
    u16*   yn     = (u16*)(ws + (5u << 20));               //  1 MB @ 5
    u16*   lnf    = (u16*)(ws + (6u << 20));               //  1 MB @ 6
    u16*   qb     = (u16*)(ws + (7u << 20));               // .5 MB @ 7
    u16*   kb     = (u16*)(ws + 7 * (1u << 20) + (1u << 19));
    u16*   vT     = (u16*)(ws + (8u << 20));               // .5 MB @ 8
    u16*   ob     = (u16*)(ws + 8 * (1u << 20) + (1u << 19));
    u16*   hbuf   = (u16*)(ws + (9u << 20));               //  4 MB @ 9
    u16*   wq16   = (u16*)(ws + (16u  << 20));             // 16 MB @ 16
    u16*   wk16   = (u16*)(ws + (32u  << 20));             // 16 MB @ 32
    u16*   wv16   = (u16*)(ws + (48u  << 20));             // 16 MB @ 48
    u16*   w1_16  = (u16*)(ws + (64u  << 20));             // 16 MB @ 64
    u16*   w2_16  = (u16*)(ws + (80u  << 20));             // 128 MB @ 80
    u16*   w3_16  = (u16*)(ws + (208u << 20));             // 128 MB @ 208

    // unified single-launch cvt: blocks = (ts, i, nt, b, kz), 16-row tiles
    Cvt6 ca;
    ca.s[0] = wq_w; ca.d[0] = wq16;  ca.N32[0] = 16;  ca.kzs[0] = 4;  ca.base[0] = 0;      // 2048
    ca.s[1] = wk_w; ca.d[1] = wk16;  ca.N32[1] = 16;  ca.kzs[1] = 4;  ca.base[1] = 2048;   // 2048
    ca.s[2] = wv_w; ca.d[2] = wv16;  ca.N32[2] = 16;  ca.kzs[2] = 4;  ca.base[2] = 4096;   // 2048
    ca.s[3] = w1;   ca.d[3] = w1_16; ca.N32[3] = 32;  ca.kzs[3] = 2;  ca.base[3] = 6144;   // 2048
    ca.s[4] = w2;   ca.d[4] = w2_16; ca.N32[4] = 128; ca.kzs[4] = 4;  ca.base[4] = 8192;   // 16384
    ca.s[5] = w3;   ca.d[5] = w3_16; ca.N32[5] = 32;  ca.kzs[5] = 16; ca.base[5] = 24576;  // 16384
    k_cvt6<<<40960, 256, 0, stream>>>(ca);

    const size_t SLAB = (size_t)16 * 16 * 1024;
    const int modes[3][2] = {{0, 1}, {2, 0}, {1, 2}};
    for (int mi = 0; mi < 3; ++mi) {
        int m1 = modes[mi][0], m2 = modes[mi][1];
        const float* s1 = (mi == 2) ? (xbuf + m1 * SLAB) : (x_in + m1 * SLAB);
        const float* s2 = (mi == 0) ? (x_in + m2 * SLAB) : (xbuf + m2 * SLAB);
        k_ln1<<<dim3(16, 8), 256, 0, stream>>>(s1, s2, lx_w, lx_b, ly_w, ly_b, a_buf, xn, yn);
        k_gemm_qkv<<<dim3(24, 16), 512, 0, stream>>>(xn, yn, wq16, wq_b, wk16, wk_b, wv16, wv_b, qb, kb, vT);
        k_attn<<<dim3(16, 4), 256, 0, stream>>>(qb, kb, vT, ob);
        k_gemm_w1<<<dim3(16, 16), 512, 0, stream>>>(ob, w1_16, b1, a_buf, x1_buf);
        k_ln2<<<dim3(16, 8), 256, 0, stream>>>(x1_buf, lf_w, lf_b, lnf);
        k_gemm_w2<<<dim3(64, 16), 256, 0, stream>>>(lnf, w2_16, b2, hbuf);
        k_gemm_w3<<<dim3(16, 16), 1024, 0, stream>>>(hbuf, w3_16, b3, x1_buf, xbuf, m1, m2);
    }
}

// Round 4
// 507.543 us; speedup vs baseline: 1.1399x; 1.0570x over previous
//
#include <hip/hip_runtime.h>

// ---------------------------------------------------------------------------
// AttentiveModes (S=16, C=1024, H=16, DH=32) on MI355X.
// Round 16. Model (validated R12/R15): READ stream caps at ~3.3 TB/s
// regardless of occupancy/mix/L3; runtime == total-read-bytes / 3.3.
// Change: mode-0's w2/w3 GEMMs are computed INSIDE the weight converter
// (k_cvtgemm): cvt phase-2's (wave,pass) already produces exactly one MFMA
// B-fragment (lane=kg*16+lr holds W[n=lr][k=kg*8..+8] for kstep kz*8+p*4+w),
// so we MFMA it against L2-hot activations while streaming. This deletes
// mode-0's 268 MB of bf16 weight reads (~81 us). qkv/w1 stay in k_cvt6;
// modes 1-2 unchanged.
// ---------------------------------------------------------------------------

#define C1024 1024
#define D512  512
#define FF4096 4096
#define NELEM 32768.0f
#define EPSLN 1e-5f
#define QSCALE 0.17677669529663687f  // 1/sqrt(32)
#define LP 258                        // LDS pitch in f32 words

typedef __attribute__((ext_vector_type(8))) short bf16x8;
typedef __attribute__((ext_vector_type(4))) float f32x4;
typedef unsigned short u16;

__device__ inline u16 f2bf(float f) {
    unsigned u = __float_as_uint(f);
    u += 0x7fffu + ((u >> 16) & 1u);
    return (u16)(u >> 16);
}

__device__ inline bf16x8 cvt8(f32x4 a, f32x4 b) {
    bf16x8 r;
    r[0] = (short)f2bf(a[0]); r[1] = (short)f2bf(a[1]);
    r[2] = (short)f2bf(a[2]); r[3] = (short)f2bf(a[3]);
    r[4] = (short)f2bf(b[0]); r[5] = (short)f2bf(b[1]);
    r[6] = (short)f2bf(b[2]); r[7] = (short)f2bf(b[3]);
    return r;
}

// ---- cvt (16-row tiles) for qkv + w1 only ---------------------------------
struct Cvt4 {
    const float* s[4];
    u16* d[4];
    int N32[4], kzs[4], base[4];
};
__global__ void __launch_bounds__(256, 8) k_cvt6(Cvt4 a) {
    __shared__ float lds[16 * LP];    // 16.5 KB
    int bid = blockIdx.x;
    int ts = 0;
#pragma unroll
    for (int j = 1; j < 4; ++j) if (bid >= a.base[j]) ts = j;
    int local = bid - a.base[ts];
    int kzs = a.kzs[ts], N32 = a.N32[ts];
    int kz = local % kzs;
    int b  = (local / kzs) & 1;
    int nt = (local / (kzs * 2)) % N32;
    int i  = local / (kzs * 2 * N32);
    int K = kzs * 256;
    int t = threadIdx.x;
    int row = t >> 4, c16 = t & 15;
    const float* Sp = a.s[ts] + ((size_t)((i * N32 + nt) * 32) + b * 16 + row) * K + kz * 256 + c16 * 4;
    float* Lrow = lds + row * LP + c16 * 4;
#pragma unroll
    for (int j = 0; j < 4; ++j) {
        f32x4 v = *(const f32x4*)(Sp + 64 * j);
        Lrow[64 * j]     = v[0];
        Lrow[64 * j + 1] = v[1];
        Lrow[64 * j + 2] = v[2];
        Lrow[64 * j + 3] = v[3];
    }
    __syncthreads();
    u16* Dp = a.d[ts] + (((size_t)(i * N32 + nt) * (kzs * 8) + kz * 8) * 1024) + b * 512;
#pragma unroll
    for (int p = 0; p < 2; ++p) {
        int u = p * 2048 + t * 8;
        int c   = u >> 9;
        int rem = u & 511;
        int kg = rem >> 7;
        int lr = (rem >> 3) & 15;
        const float* src = lds + lr * LP + c * 32 + kg * 8;
        f32x4 lo, hi;
        lo[0] = src[0]; lo[1] = src[1]; lo[2] = src[2]; lo[3] = src[3];
        hi[0] = src[4]; hi[1] = src[5]; hi[2] = src[6]; hi[3] = src[7];
        *(bf16x8*)(Dp + c * 1024 + rem) = cvt8(lo, hi);
    }
}

// ---- fused cvt + mode-0 GEMM ----------------------------------------------
// Block (bx = nt*2 + b, i): streams W32 rows [nt*32 + b*16, +16) over full K
// in 256-k slices; converts + stores swizzled bf16 chunks (identical layout
// to k_cvt6) AND accumulates act @ W^T via MFMA. Wave w pass p holds the
// B-fragment for kstep kz*8 + p*4 + w. acc reduced across waves in LDS.
// EPI 0: gelu(acc + bias) -> hb (w2).  EPI 1: acc + bias + x1 -> xout (w3).
template<int EPI>
__global__ void __launch_bounds__(256, 4)
k_cvtgemm(const float* __restrict__ W32, u16* __restrict__ W16,
          const u16* __restrict__ act, int kzs, int N32,
          const float* __restrict__ bias,
          u16* __restrict__ hb,
          const float* __restrict__ x1, float* __restrict__ xout,
          int m1, int m2) {
    __shared__ float lds[16 * LP];      // 16.5 KB staging
    __shared__ float Pl[4][32][16];     // 8 KB partials
    int bx = blockIdx.x, i = blockIdx.y;
    int b = bx & 1, nt = bx >> 1;
    int K = kzs * 256;
    int t = threadIdx.x;
    int w = t >> 6, lane = t & 63;
    int lr = lane & 15, kg = lane >> 4;
    int row = t >> 4, c16 = t & 15;
    const float* Sp = W32 + ((size_t)(i * N32 + nt) * 32 + b * 16 + row) * K + c16 * 4;
    u16* Dbase = W16 + ((size_t)(i * N32 + nt) * (kzs * 8)) * 1024 + b * 512;
    const u16* A0 = act + ((size_t)(i * 32) + lr) * K + kg * 8;
    const u16* A1 = A0 + (size_t)16 * K;
    f32x4 acc0 = {0.f, 0.f, 0.f, 0.f}, acc1 = {0.f, 0.f, 0.f, 0.f};
    float* Lrow = lds + row * LP + c16 * 4;
    const float* src = lds + lr * LP + kg * 8;
    for (int kz = 0; kz < kzs; ++kz) {
        const float* Sk = Sp + kz * 256;
#pragma unroll
        for (int j = 0; j < 4; ++j) {
            f32x4 v = *(const f32x4*)(Sk + 64 * j);
            Lrow[64 * j]     = v[0];
            Lrow[64 * j + 1] = v[1];
            Lrow[64 * j + 2] = v[2];
            Lrow[64 * j + 3] = v[3];
        }
        __syncthreads();
        u16* Dp = Dbase + (size_t)(kz * 8) * 1024;
#pragma unroll
        for (int p = 0; p < 2; ++p) {
            int c = p * 4 + w;
            const float* s8 = src + c * 32;
            f32x4 lo, hi;
            lo[0] = s8[0]; lo[1] = s8[1]; lo[2] = s8[2]; lo[3] = s8[3];
            hi[0] = s8[4]; hi[1] = s8[5]; hi[2] = s8[6]; hi[3] = s8[7];
            bf16x8 r = cvt8(lo, hi);
            *(bf16x8*)(Dp + c * 1024 + lane * 8) = r;
            int kk = kz * 8 + c;
            bf16x8 aF0 = *(const bf16x8*)(A0 + kk * 32);
            bf16x8 aF1 = *(const bf16x8*)(A1 + kk * 32);
            acc0 = __builtin_amdgcn_mfma_f32_16x16x32_bf16(aF0, r, acc0, 0, 0, 0);
            acc1 = __builtin_amdgcn_mfma_f32_16x16x32_bf16(aF1, r, acc1, 0, 0, 0);
        }
        __syncthreads();
    }
#pragma unroll
    for (int rr = 0; rr < 4; ++rr) {
        Pl[w][kg * 4 + rr][lr]      = acc0[rr];
        Pl[w][16 + kg * 4 + rr][lr] = acc1[rr];
    }
    __syncthreads();
    int m = t >> 3, nl0 = (t & 7) * 2;
#pragma unroll
    for (int jj = 0; jj < 2; ++jj) {
        int nl = nl0 + jj;
        float v = Pl[0][m][nl] + Pl[1][m][nl] + Pl[2][m][nl] + Pl[3][m][nl];
        int n = nt * 32 + b * 16 + nl;
        if constexpr (EPI == 0) {
            float tt = v + bias[i * FF4096 + n];
            float g = 0.5f * tt * (1.f + erff(tt * 0.70710678118654752f));
            hb[((size_t)(i * 32) + m) * FF4096 + n] = f2bf(g);
        } else {
            int base = ((i * 32 + m) << 10) + n;
            float vv = v + bias[i * C1024 + n] + x1[base];
            int dst = (m < 16) ? (((m1 * 16 + i) * 16 + m) << 10)
                               : (((m2 * 16 + i) * 16 + (m - 16)) << 10);
            xout[dst + n] = vv;
        }
    }
}

// swizzled-weight inner loop: p pre-offset by lane*8; 1KB/frag contiguous.
__device__ inline void mmz(const u16* __restrict__ act, const u16* __restrict__ p,
                           int nkk, f32x4& acc0, f32x4& acc1) {
#pragma unroll 4
    for (int j = 0; j < nkk; ++j) {
        bf16x8 aF = *(const bf16x8*)(act + j * 32);
        bf16x8 b0 = *(const bf16x8*)(p + (size_t)j * 1024);
        bf16x8 b1 = *(const bf16x8*)(p + (size_t)j * 1024 + 512);
        acc0 = __builtin_amdgcn_mfma_f32_16x16x32_bf16(aF, b0, acc0, 0, 0, 0);
        acc1 = __builtin_amdgcn_mfma_f32_16x16x32_bf16(aF, b1, acc1, 0, 0, 0);
    }
}

// 256-thread block reduce of (s,q); lds >= 10 floats.
__device__ inline void reduce256(float& s, float& q, int t, float* lds) {
    for (int off = 32; off; off >>= 1) {
        s += __shfl_down(s, off, 64);
        q += __shfl_down(q, off, 64);
    }
    int wv = t >> 6;
    if ((t & 63) == 0) { lds[wv * 2] = s; lds[wv * 2 + 1] = q; }
    __syncthreads();
    if (t == 0) {
        lds[8] = lds[0] + lds[2] + lds[4] + lds[6];
        lds[9] = lds[1] + lds[3] + lds[5] + lds[7];
    }
    __syncthreads();
    s = lds[8]; q = lds[9];
}

// ---- LN1 ------------------------------------------------------------------
__global__ void k_ln1(const float* __restrict__ s1, const float* __restrict__ s2,
                      const float* __restrict__ gw, const float* __restrict__ gb,
                      const float* __restrict__ hw, const float* __restrict__ hb,
                      float* __restrict__ a_buf,
                      u16* __restrict__ xn, u16* __restrict__ yn) {
    __shared__ float lds[10];
    int i = blockIdx.x, cb = blockIdx.y, t = threadIdx.x;
    float s = 0.f, q = 0.f;
#pragma unroll 4
    for (int rr = 0; rr < 32; ++rr) {
        const float* src = (rr < 16)
            ? (s1 + ((i * 16 + rr) << 10))
            : (s2 + (((rr - 16) * 16 + i) << 10));
        f32x4 v = *(const f32x4*)(src + t * 4);
        s += v[0] + v[1] + v[2] + v[3];
        q += v[0]*v[0] + v[1]*v[1] + v[2]*v[2] + v[3]*v[3];
        if ((t >> 5) == cb)
            *(f32x4*)(a_buf + ((i * 32 + rr) << 10) + t * 4) = v;
    }
    reduce256(s, q, t, lds);
    float mean = s * (1.f / NELEM);
    float var = q * (1.f / NELEM) - mean * mean;
    float inv = rsqrtf(var + EPSLN);
    int c = cb * 128 + (t & 31) * 4;
    int r0 = (t >> 5) * 4;
#pragma unroll
    for (int rr = 0; rr < 4; ++rr) {
        int row = r0 + rr;
        const float* src = (row < 16)
            ? (s1 + ((i * 16 + row) << 10))
            : (s2 + (((row - 16) * 16 + i) << 10));
        f32x4 v = *(const f32x4*)(src + c);
        int base = ((i * 32 + row) << 10) + c;
        f32x4 gwv = *(const f32x4*)(gw + base);
        f32x4 gbv = *(const f32x4*)(gb + base);
        f32x4 hwv = *(const f32x4*)(hw + base);
        f32x4 hbv = *(const f32x4*)(hb + base);
        float z0 = (v[0]-mean)*inv, z1 = (v[1]-mean)*inv, z2 = (v[2]-mean)*inv, z3 = (v[3]-mean)*inv;
        uint2 a, b;
        a.x = (unsigned)f2bf(z0*gwv[0]+gbv[0]) | ((unsigned)f2bf(z1*gwv[1]+gbv[1]) << 16);
        a.y = (unsigned)f2bf(z2*gwv[2]+gbv[2]) | ((unsigned)f2bf(z3*gwv[3]+gbv[3]) << 16);
        b.x = (unsigned)f2bf(z0*hwv[0]+hbv[0]) | ((unsigned)f2bf(z1*hwv[1]+hbv[1]) << 16);
        b.y = (unsigned)f2bf(z2*hwv[2]+hbv[2]) | ((unsigned)f2bf(z3*hwv[3]+hbv[3]) << 16);
        *(uint2*)(xn + base) = a;
        *(uint2*)(yn + base) = b;
    }
}

// ---- LN2 ------------------------------------------------------------------
__global__ void k_ln2(const float* __restrict__ x1,
                      const float* __restrict__ gw, const float* __restrict__ gb,
                      u16* __restrict__ out) {
    __shared__ float lds[10];
    int i = blockIdx.x, cb = blockIdx.y, t = threadIdx.x;
    float s = 0.f, q = 0.f;
#pragma unroll 4
    for (int rr = 0; rr < 32; ++rr) {
        f32x4 v = *(const f32x4*)(x1 + ((i * 32 + rr) << 10) + t * 4);
        s += v[0] + v[1] + v[2] + v[3];
        q += v[0]*v[0] + v[1]*v[1] + v[2]*v[2] + v[3]*v[3];
    }
    reduce256(s, q, t, lds);
    float mean = s * (1.f / NELEM);
    float var = q * (1.f / NELEM) - mean * mean;
    float inv = rsqrtf(var + EPSLN);
    int c = cb * 128 + (t & 31) * 4;
    int r0 = (t >> 5) * 4;
#pragma unroll
    for (int rr = 0; rr < 4; ++rr) {
        int base = ((i * 32 + r0 + rr) << 10) + c;
        f32x4 v  = *(const f32x4*)(x1 + base);
        f32x4 gwv = *(const f32x4*)(gw + base);
        f32x4 gbv = *(const f32x4*)(gb + base);
        float z0 = (v[0]-mean)*inv, z1 = (v[1]-mean)*inv, z2 = (v[2]-mean)*inv, z3 = (v[3]-mean)*inv;
        uint2 a;
        a.x = (unsigned)f2bf(z0*gwv[0]+gbv[0]) | ((unsigned)f2bf(z1*gwv[1]+gbv[1]) << 16);
        a.y = (unsigned)f2bf(z2*gwv[2]+gbv[2]) | ((unsigned)f2bf(z3*gwv[3]+gbv[3]) << 16);
        *(uint2*)(out + base) = a;
    }
}

// ---- QKV GEMM -------------------------------------------------------------
__global__ void __launch_bounds__(512, 4)
k_gemm_qkv(const u16* __restrict__ xn, const u16* __restrict__ yn,
           const u16* __restrict__ wq, const float* __restrict__ wqb,
           const u16* __restrict__ wk, const float* __restrict__ wkb,
           const u16* __restrict__ wv, const float* __restrict__ wvb,
           u16* __restrict__ qo, u16* __restrict__ ko, u16* __restrict__ vT) {
    __shared__ float Pl[2][32][64];
    int bx = blockIdx.x, i = blockIdx.y;
    int w = threadIdx.x >> 6, lane = threadIdx.x & 63;
    int kh = w >> 2, mh = (w >> 1) & 1, wn = w & 1;
    int lr = lane & 15, kg = lane >> 4;
    int sel = bx >> 3;
    int ntl = (bx - sel * 8) * 2 + wn;
    const u16* act = (sel == 0 ? xn : yn) + (i * 32 + mh * 16 + lr) * C1024 + kh * 512 + kg * 8;
    const u16* Wm = (sel == 0 ? wq : (sel == 1 ? wk : wv));
    const u16* p = Wm + (((size_t)i * 16 + ntl) * 32 + kh * 16) * 1024 + lane * 8;
    f32x4 a0 = {0.f, 0.f, 0.f, 0.f}, a1 = {0.f, 0.f, 0.f, 0.f};
    mmz(act, p, 16, a0, a1);
    int m0 = mh * 16 + kg * 4;
#pragma unroll
    for (int r = 0; r < 4; ++r) {
        Pl[kh][m0 + r][wn * 32 + lr] = a0[r];
        Pl[kh][m0 + r][wn * 32 + 16 + lr] = a1[r];
    }
    __syncthreads();
    int t = threadIdx.x;
    int row = t >> 4, c0 = (t & 15) * 4;
    int nloc = bx * 64 - sel * 512 + c0;
    const float* bias = (sel == 0 ? wqb : (sel == 1 ? wkb : wvb)) + i * D512 + nloc;
    float v0 = Pl[0][row][c0]     + Pl[1][row][c0]     + bias[0];
    float v1 = Pl[0][row][c0 + 1] + Pl[1][row][c0 + 1] + bias[1];
    float v2 = Pl[0][row][c0 + 2] + Pl[1][row][c0 + 2] + bias[2];
    float v3 = Pl[0][row][c0 + 3] + Pl[1][row][c0 + 3] + bias[3];
    if (sel == 0) {
        uint2 a;
        a.x = (unsigned)f2bf(v0 * QSCALE) | ((unsigned)f2bf(v1 * QSCALE) << 16);
        a.y = (unsigned)f2bf(v2 * QSCALE) | ((unsigned)f2bf(v3 * QSCALE) << 16);
        *(uint2*)(qo + (i * 32 + row) * D512 + nloc) = a;
    } else if (sel == 1) {
        uint2 a;
        a.x = (unsigned)f2bf(v0) | ((unsigned)f2bf(v1) << 16);
        a.y = (unsigned)f2bf(v2) | ((unsigned)f2bf(v3) << 16);
        *(uint2*)(ko + (i * 32 + row) * D512 + nloc) = a;
    } else {
        int h = nloc >> 5, d = nloc & 31;
        u16* vb = vT + ((i * 16 + h) * 32 + d) * 32 + row;
        vb[0]  = f2bf(v0);
        vb[32] = f2bf(v1);
        vb[64] = f2bf(v2);
        vb[96] = f2bf(v3);
    }
}

// ---- attention per (idx, head) --------------------------------------------
__global__ void k_attn(const u16* __restrict__ q, const u16* __restrict__ k,
                       const u16* __restrict__ vT, u16* __restrict__ o) {
    __shared__ __align__(16) u16 Sm[4][32][32];
    int i = blockIdx.x;
    int w = threadIdx.x >> 6, lane = threadIdx.x & 63;
    int h = blockIdx.y * 4 + w;
    int lr = lane & 15, kg = lane >> 4;
    const u16* qb = q + i * 32 * D512 + h * 32 + kg * 8;
    const u16* kb = k + i * 32 * D512 + h * 32 + kg * 8;
    bf16x8 a0 = *(const bf16x8*)(qb + lr * D512);
    bf16x8 a1 = *(const bf16x8*)(qb + (16 + lr) * D512);
    bf16x8 b0 = *(const bf16x8*)(kb + lr * D512);
    bf16x8 b1 = *(const bf16x8*)(kb + (16 + lr) * D512);
    f32x4 z = {0.f, 0.f, 0.f, 0.f};
    f32x4 s00 = __builtin_amdgcn_mfma_f32_16x16x32_bf16(a0, b0, z, 0, 0, 0);
    f32x4 s01 = __builtin_amdgcn_mfma_f32_16x16x32_bf16(a0, b1, z, 0, 0, 0);
    f32x4 s10 = __builtin_amdgcn_mfma_f32_16x16x32_bf16(a1, b0, z, 0, 0, 0);
    f32x4 s11 = __builtin_amdgcn_mfma_f32_16x16x32_bf16(a1, b1, z, 0, 0, 0);
    int mr = kg * 4;
#pragma unroll
    for (int r = 0; r < 4; ++r) {
        Sm[w][mr + r][lr]           = f2bf(s00[r]);
        Sm[w][mr + r][16 + lr]      = f2bf(s01[r]);
        Sm[w][16 + mr + r][lr]      = f2bf(s10[r]);
        Sm[w][16 + mr + r][16 + lr] = f2bf(s11[r]);
    }
    __syncthreads();
    bf16x8 p0 = *(const bf16x8*)&Sm[w][lr][kg * 8];
    bf16x8 p1 = *(const bf16x8*)&Sm[w][16 + lr][kg * 8];
    const u16* vb = vT + (i * 16 + h) * 32 * 32 + kg * 8;
    bf16x8 v0 = *(const bf16x8*)(vb + lr * 32);
    bf16x8 v1 = *(const bf16x8*)(vb + (16 + lr) * 32);
    f32x4 o00 = __builtin_amdgcn_mfma_f32_16x16x32_bf16(p0, v0, z, 0, 0, 0);
    f32x4 o01 = __builtin_amdgcn_mfma_f32_16x16x32_bf16(p0, v1, z, 0, 0, 0);
    f32x4 o10 = __builtin_amdgcn_mfma_f32_16x16x32_bf16(p1, v0, z, 0, 0, 0);
    f32x4 o11 = __builtin_amdgcn_mfma_f32_16x16x32_bf16(p1, v1, z, 0, 0, 0);
#pragma unroll
    for (int r = 0; r < 4; ++r) {
        o[(i * 32 + mr + r) * D512 + h * 32 + lr]           = f2bf(o00[r]);
        o[(i * 32 + mr + r) * D512 + h * 32 + 16 + lr]      = f2bf(o01[r]);
        o[(i * 32 + 16 + mr + r) * D512 + h * 32 + lr]      = f2bf(o10[r]);
        o[(i * 32 + 16 + mr + r) * D512 + h * 32 + 16 + lr] = f2bf(o11[r]);
    }
}

// ---- w1 GEMM --------------------------------------------------------------
__global__ void __launch_bounds__(512, 4)
k_gemm_w1(const u16* __restrict__ ob, const u16* __restrict__ W,
          const float* __restrict__ bias, const float* __restrict__ a_buf,
          float* __restrict__ x1) {
    __shared__ float Pl[2][32][64];
    int bx = blockIdx.x, i = blockIdx.y;
    int w = threadIdx.x >> 6, lane = threadIdx.x & 63;
    int kh = w >> 2, mh = (w >> 1) & 1, wn = w & 1;
    int lr = lane & 15, kg = lane >> 4;
    int nt = bx * 2 + wn;
    const u16* act = ob + (i * 32 + mh * 16 + lr) * D512 + kh * 256 + kg * 8;
    const u16* p = W + (((size_t)i * 32 + nt) * 16 + kh * 8) * 1024 + lane * 8;
    f32x4 a0 = {0.f, 0.f, 0.f, 0.f}, a1 = {0.f, 0.f, 0.f, 0.f};
    mmz(act, p, 8, a0, a1);
    int m0 = mh * 16 + kg * 4;
#pragma unroll
    for (int r = 0; r < 4; ++r) {
        Pl[kh][m0 + r][wn * 32 + lr] = a0[r];
        Pl[kh][m0 + r][wn * 32 + 16 + lr] = a1[r];
    }
    __syncthreads();
    int t = threadIdx.x;
    int row = t >> 4, c0 = (t & 15) * 4;
    int n = bx * 64 + c0;
    int base = ((i * 32 + row) << 10) + n;
    f32x4 bv = *(const f32x4*)(bias + i * C1024 + n);
    f32x4 av = *(const f32x4*)(a_buf + base);
    f32x4 r;
    r[0] = Pl[0][row][c0]     + Pl[1][row][c0]     + bv[0] + av[0];
    r[1] = Pl[0][row][c0 + 1] + Pl[1][row][c0 + 1] + bv[1] + av[1];
    r[2] = Pl[0][row][c0 + 2] + Pl[1][row][c0 + 2] + bv[2] + av[2];
    r[3] = Pl[0][row][c0 + 3] + Pl[1][row][c0 + 3] + bv[3] + av[3];
    *(f32x4*)(x1 + base) = r;
}

// ---- w2 GEMM (modes 1-2) --------------------------------------------------
__global__ void __launch_bounds__(256, 4)
k_gemm_w2(const u16* __restrict__ lnf, const u16* __restrict__ W,
          const float* __restrict__ bias, u16* __restrict__ hb) {
    int bx = blockIdx.x, i = blockIdx.y;
    int w = threadIdx.x >> 6, lane = threadIdx.x & 63;
    int mh = w & 1, wn = w >> 1, lr = lane & 15, kg = lane >> 4;
    int nt = bx * 2 + wn;
    const u16* act = lnf + (i * 32 + mh * 16 + lr) * C1024 + kg * 8;
    const u16* p = W + (((size_t)i * 128 + nt) * 32) * 1024 + lane * 8;
    f32x4 a0 = {0.f, 0.f, 0.f, 0.f}, a1 = {0.f, 0.f, 0.f, 0.f};
    mmz(act, p, 32, a0, a1);
    int m0 = mh * 16 + kg * 4;
    int nb = bx * 64 + wn * 32;
    int n0 = nb + lr, n1 = nb + 16 + lr;
    float b0 = bias[i * FF4096 + n0], b1 = bias[i * FF4096 + n1];
#pragma unroll
    for (int r = 0; r < 4; ++r) {
        float t0 = a0[r] + b0;
        float t1 = a1[r] + b1;
        float g0 = 0.5f * t0 * (1.f + erff(t0 * 0.70710678118654752f));
        float g1 = 0.5f * t1 * (1.f + erff(t1 * 0.70710678118654752f));
        hb[(i * 32 + m0 + r) * FF4096 + n0] = f2bf(g0);
        hb[(i * 32 + m0 + r) * FF4096 + n1] = f2bf(g1);
    }
}

// ---- w3 GEMM (modes 1-2) --------------------------------------------------
__global__ void __launch_bounds__(1024, 4)
k_gemm_w3(const u16* __restrict__ hb, const u16* __restrict__ W,
          const float* __restrict__ bias, const float* __restrict__ x1,
          float* __restrict__ xout, int m1, int m2) {
    __shared__ float Pl[4][32][64];
    int bx = blockIdx.x, i = blockIdx.y;
    int w = threadIdx.x >> 6, lane = threadIdx.x & 63;
    int kq = w >> 2, mh = (w >> 1) & 1, wn = w & 1;
    int lr = lane & 15, kg = lane >> 4;
    int nt = bx * 2 + wn;
    const u16* act = hb + (i * 32 + mh * 16 + lr) * FF4096 + kq * 1024 + kg * 8;
    const u16* p = W + (((size_t)i * 32 + nt) * 128 + kq * 32) * 1024 + lane * 8;
    f32x4 a0 = {0.f, 0.f, 0.f, 0.f}, a1 = {0.f, 0.f, 0.f, 0.f};
    mmz(act, p, 32, a0, a1);
    int m0 = mh * 16 + kg * 4;
#pragma unroll
    for (int r = 0; r < 4; ++r) {
        Pl[kq][m0 + r][wn * 32 + lr] = a0[r];
        Pl[kq][m0 + r][wn * 32 + 16 + lr] = a1[r];
    }
    __syncthreads();
    int t = threadIdx.x;
    int row = t >> 5, c0 = (t & 31) * 2;
    int n = bx * 64 + c0;
    int dst = (row < 16) ? (((m1 * 16 + i) * 16 + row) << 10)
                         : (((m2 * 16 + i) * 16 + (row - 16)) << 10);
    int base = ((i * 32 + row) << 10) + n;
#pragma unroll
    for (int j = 0; j < 2; ++j) {
        float v = Pl[0][row][c0 + j] + Pl[1][row][c0 + j]
                + Pl[2][row][c0 + j] + Pl[3][row][c0 + j]
                + bias[i * C1024 + n + j] + x1[base + j];
        xout[dst + n + j] = v;
    }
}

// ---------------------------------------------------------------------------
extern "C" void kernel_launch(void* const* d_in, const int* in_sizes, int n_in,
                              void* d_out, int out_size, void* d_ws, size_t ws_size,
                              hipStream_t stream) {
    const float* x_in = (const float*)d_in[0];
    const float* lx_w = (const float*)d_in[1];
    const float* lx_b = (const float*)d_in[2];
    const float* ly_w = (const float*)d_in[3];
    const float* ly_b = (const float*)d_in[4];
    const float* lf_w = (const float*)d_in[5];
    const float* lf_b = (const float*)d_in[6];
    const float* wq_w = (const float*)d_in[7];
    const float* wq_b = (const float*)d_in[8];
    const float* wk_w = (const float*)d_in[9];
    const float* wk_b = (const float*)d_in[10];
    const float* wv_w = (const float*)d_in[11];
    const float* wv_b = (const float*)d_in[12];
    const float* w1   = (const float*)d_in[13];
    const float* b1   = (const float*)d_in[14];
    const float* w2   = (const float*)d_in[15];
    const float* b2   = (const float*)d_in[16];
    const float* w3   = (const float*)d_in[17];
    const float* b3   = (const float*)d_in[18];

    float* xbuf = (float*)d_out;   // working state x [3][16][16][1024]
    char* ws = (char*)d_ws;
    float* a_buf  = (float*)(ws);                          //  2 MB @ 0
    float* x1_buf = (float*)(ws + (2u << 20));             //  2 MB @ 2
    u16*   xn     = (u16*)(ws + (4u << 20));               //  1 MB @ 4
    u16*   yn     = (u16*)(ws + (5u << 20));               //  1 MB @ 5
    u16*   lnf    = (u16*)(ws + (6u << 20));               //  1 MB @ 6
    u16*   qb     = (u16*)(ws + (7u << 20));               // .5 MB @ 7
    u16*   kb     = (u16*)(ws + 7 * (1u << 20) + (1u << 19));
    u16*   vT     = (u16*)(ws + (8u << 20));               // .5 MB @ 8
    u16*   ob     = (u16*)(ws + 8 * (1u << 20) + (1u << 19));
    u16*   hbuf   = (u16*)(ws + (9u << 20));               //  4 MB @ 9
    u16*   wq16   = (u16*)(ws + (16u  << 20));             // 16 MB @ 16
    u16*   wk16   = (u16*)(ws + (32u  << 20));             // 16 MB @ 32
    u16*   wv16   = (u16*)(ws + (48u  << 20));             // 16 MB @ 48
    u16*   w1_16  = (u16*)(ws + (64u  << 20));             // 16 MB @ 64
    u16*   w2_16  = (u16*)(ws + (80u  << 20));             // 128 MB @ 80
    u16*   w3_16  = (u16*)(ws + (208u << 20));             // 128 MB @ 208

    // cvt for qkv + w1 weights only (w2/w3 handled by fused kernels)
    Cvt4 ca;
    ca.s[0] = wq_w; ca.d[0] = wq16;  ca.N32[0] = 16;  ca.kzs[0] = 4;  ca.base[0] = 0;      // 2048
    ca.s[1] = wk_w; ca.d[1] = wk16;  ca.N32[1] = 16;  ca.kzs[1] = 4;  ca.base[1] = 2048;   // 2048
    ca.s[2] = wv_w; ca.d[2] = wv16;  ca.N32[2] = 16;  ca.kzs[2] = 4;  ca.base[2] = 4096;   // 2048
    ca.s[3] = w1;   ca.d[3] = w1_16; ca.N32[3] = 32;  ca.kzs[3] = 2;  ca.base[3] = 6144;   // 2048
    k_cvt6<<<8192, 256, 0, stream>>>(ca);

    const size_t SLAB = (size_t)16 * 16 * 1024;
    const int modes[3][2] = {{0, 1}, {2, 0}, {1, 2}};
    for (int mi = 0; mi < 3; ++mi) {
        int m1 = modes[mi][0], m2 = modes[mi][1];
        const float* s1 = (mi == 2) ? (xbuf + m1 * SLAB) : (x_in + m1 * SLAB);
        const float* s2 = (mi == 0) ? (x_in + m2 * SLAB) : (xbuf + m2 * SLAB);
        k_ln1<<<dim3(16, 8), 256, 0, stream>>>(s1, s2, lx_w, lx_b, ly_w, ly_b, a_buf, xn, yn);
        k_gemm_qkv<<<dim3(24, 16), 512, 0, stream>>>(xn, yn, wq16, wq_b, wk16, wk_b, wv16, wv_b, qb, kb, vT);
        k_attn<<<dim3(16, 4), 256, 0, stream>>>(qb, kb, vT, ob);
        k_gemm_w1<<<dim3(16, 16), 512, 0, stream>>>(ob, w1_16, b1, a_buf, x1_buf);
        k_ln2<<<dim3(16, 8), 256, 0, stream>>>(x1_buf, lf_w, lf_b, lnf);
        if (mi == 0) {
            // fused: convert w2/w3 AND compute mode-0's GEMMs while streaming
            k_cvtgemm<0><<<dim3(256, 16), 256, 0, stream>>>(
                w2, w2_16, lnf, 4, 128, b2, hbuf, nullptr, nullptr, 0, 0);
            k_cvtgemm<1><<<dim3(64, 16), 256, 0, stream>>>(
                w3, w3_16, hbuf, 16, 32, b3, nullptr, x1_buf, xbuf, m1, m2);
        } else {
            k_gemm_w2<<<dim3(64, 16), 256, 0, stream>>>(lnf, w2_16, b2, hbuf);
            k_gemm_w3<<<dim3(16, 16), 1024, 0, stream>>>(hbuf, w3_16, b3, x1_buf, xbuf, m1, m2);
        }
    }
}

// Round 5
// 500.511 us; speedup vs baseline: 1.1559x; 1.0140x over previous
//
#include <hip/hip_runtime.h>

// ---------------------------------------------------------------------------
// AttentiveModes (S=16, C=1024, H=16, DH=32) on MI355X.
// Round 17. R16 validated cvt+GEMM fusion (536->507). This round:
// (1) fusion extended to qkv + w1 (k_cvt6 deleted; mode-0 reads fp32 weights
//     exactly once, saves mode-0's 67MB bf16 weight re-read),
// (2) register-prefetch double-buffer in all fused kernels: next 256-k slice
//     loaded to regs during phase-2 compute; vmcnt waited only at next LDS
//     write -> HBM latency hidden (R16's fused kernels were latency-exposed).
// Modes 1-2 unchanged (bf16 swizzled-chunk GEMMs at the ~3.4 TB/s read cap).
// ---------------------------------------------------------------------------

#define C1024 1024
#define D512  512
#define FF4096 4096
#define NELEM 32768.0f
#define EPSLN 1e-5f
#define QSCALE 0.17677669529663687f  // 1/sqrt(32)
#define LP 258                        // LDS pitch in f32 words

typedef __attribute__((ext_vector_type(8))) short bf16x8;
typedef __attribute__((ext_vector_type(4))) float f32x4;
typedef unsigned short u16;

__device__ inline u16 f2bf(float f) {
    unsigned u = __float_as_uint(f);
    u += 0x7fffu + ((u >> 16) & 1u);
    return (u16)(u >> 16);
}

__device__ inline bf16x8 cvt8(f32x4 a, f32x4 b) {
    bf16x8 r;
    r[0] = (short)f2bf(a[0]); r[1] = (short)f2bf(a[1]);
    r[2] = (short)f2bf(a[2]); r[3] = (short)f2bf(a[3]);
    r[4] = (short)f2bf(b[0]); r[5] = (short)f2bf(b[1]);
    r[6] = (short)f2bf(b[2]); r[7] = (short)f2bf(b[3]);
    return r;
}

// ---- shared fused-body: stream 16 rows x K fp32, cvt+store bf16 chunks,
// MFMA against act rows. Register-prefetched double-buffer.
// Wave w, pass p computes k-step kz*8 + p*4 + w; acc0/acc1 = m 0-15/16-31.
__device__ inline void cvtgemm_body(const float* __restrict__ Sp,
                                    u16* __restrict__ Dbase,
                                    const u16* __restrict__ A0,
                                    const u16* __restrict__ A1,
                                    int kzs, int t, int w, int lane,
                                    float* lds, f32x4& acc0, f32x4& acc1) {
    int row = t >> 4, c16 = t & 15;
    int lr = lane & 15, kg = lane >> 4;
    float* Lrow = lds + row * LP + c16 * 4;
    const float* src = lds + lr * LP + kg * 8;
    f32x4 rv0 = *(const f32x4*)(Sp);
    f32x4 rv1 = *(const f32x4*)(Sp + 64);
    f32x4 rv2 = *(const f32x4*)(Sp + 128);
    f32x4 rv3 = *(const f32x4*)(Sp + 192);
    for (int kz = 0; kz < kzs; ++kz) {
        Lrow[0]   = rv0[0]; Lrow[1]   = rv0[1]; Lrow[2]   = rv0[2]; Lrow[3]   = rv0[3];
        Lrow[64]  = rv1[0]; Lrow[65]  = rv1[1]; Lrow[66]  = rv1[2]; Lrow[67]  = rv1[3];
        Lrow[128] = rv2[0]; Lrow[129] = rv2[1]; Lrow[130] = rv2[2]; Lrow[131] = rv2[3];
        Lrow[192] = rv3[0]; Lrow[193] = rv3[1]; Lrow[194] = rv3[2]; Lrow[195] = rv3[3];
        __syncthreads();
        if (kz + 1 < kzs) {
            const float* Sk = Sp + (kz + 1) * 256;
            rv0 = *(const f32x4*)(Sk);
            rv1 = *(const f32x4*)(Sk + 64);
            rv2 = *(const f32x4*)(Sk + 128);
            rv3 = *(const f32x4*)(Sk + 192);
        }
        u16* Dp = Dbase + (size_t)(kz * 8) * 1024;
#pragma unroll
        for (int p = 0; p < 2; ++p) {
            int c = p * 4 + w;
            const float* s8 = src + c * 32;
            f32x4 lo, hi;
            lo[0] = s8[0]; lo[1] = s8[1]; lo[2] = s8[2]; lo[3] = s8[3];
            hi[0] = s8[4]; hi[1] = s8[5]; hi[2] = s8[6]; hi[3] = s8[7];
            bf16x8 r = cvt8(lo, hi);
            *(bf16x8*)(Dp + c * 1024 + lane * 8) = r;
            int kk = kz * 8 + c;
            bf16x8 aF0 = *(const bf16x8*)(A0 + kk * 32);
            bf16x8 aF1 = *(const bf16x8*)(A1 + kk * 32);
            acc0 = __builtin_amdgcn_mfma_f32_16x16x32_bf16(aF0, r, acc0, 0, 0, 0);
            acc1 = __builtin_amdgcn_mfma_f32_16x16x32_bf16(aF1, r, acc1, 0, 0, 0);
        }
        __syncthreads();
    }
}

// ---- fused cvt + mode-0 GEMM (generic epilogues) --------------------------
// EPI 0: gelu(acc+bias) -> hb (w2).  EPI 1: acc+bias+x1 -> xout (w3).
// EPI 2: acc+bias+a_buf -> x1 (w1, f32 out).
template<int EPI>
__global__ void __launch_bounds__(256, 4)
k_cvtgemm(const float* __restrict__ W32, u16* __restrict__ W16,
          const u16* __restrict__ act, int kzs, int N32,
          const float* __restrict__ bias,
          u16* __restrict__ hb,
          const float* __restrict__ x1, float* __restrict__ xout,
          const float* __restrict__ a_buf,
          int m1, int m2) {
    __shared__ float lds[16 * LP];      // 16.5 KB staging
    __shared__ float Pl[4][32][16];     // 8 KB partials
    int bx = blockIdx.x, i = blockIdx.y;
    int b = bx & 1, nt = bx >> 1;
    int K = kzs * 256;
    int t = threadIdx.x;
    int w = t >> 6, lane = t & 63;
    int lr = lane & 15, kg = lane >> 4;
    const float* Sp = W32 + ((size_t)(i * N32 + nt) * 32 + b * 16 + (t >> 4)) * K + (t & 15) * 4;
    u16* Dbase = W16 + ((size_t)(i * N32 + nt) * (kzs * 8)) * 1024 + b * 512;
    const u16* A0 = act + ((size_t)(i * 32) + lr) * K + kg * 8;
    const u16* A1 = A0 + (size_t)16 * K;
    f32x4 acc0 = {0.f, 0.f, 0.f, 0.f}, acc1 = {0.f, 0.f, 0.f, 0.f};
    cvtgemm_body(Sp, Dbase, A0, A1, kzs, t, w, lane, lds, acc0, acc1);
#pragma unroll
    for (int rr = 0; rr < 4; ++rr) {
        Pl[w][kg * 4 + rr][lr]      = acc0[rr];
        Pl[w][16 + kg * 4 + rr][lr] = acc1[rr];
    }
    __syncthreads();
    int m = t >> 3, nl0 = (t & 7) * 2;
#pragma unroll
    for (int jj = 0; jj < 2; ++jj) {
        int nl = nl0 + jj;
        float v = Pl[0][m][nl] + Pl[1][m][nl] + Pl[2][m][nl] + Pl[3][m][nl];
        int n = nt * 32 + b * 16 + nl;
        if constexpr (EPI == 0) {
            float tt = v + bias[i * FF4096 + n];
            float g = 0.5f * tt * (1.f + erff(tt * 0.70710678118654752f));
            hb[((size_t)(i * 32) + m) * FF4096 + n] = f2bf(g);
        } else if constexpr (EPI == 1) {
            int base = ((i * 32 + m) << 10) + n;
            float vv = v + bias[i * C1024 + n] + x1[base];
            int dst = (m < 16) ? (((m1 * 16 + i) * 16 + m) << 10)
                               : (((m2 * 16 + i) * 16 + (m - 16)) << 10);
            xout[dst + n] = vv;
        } else {
            int base = ((i * 32 + m) << 10) + n;
            xout[base] = v + bias[i * C1024 + n] + a_buf[base];
        }
    }
}

// ---- fused cvt + mode-0 QKV GEMM (merged q/k/v, runtime sel) --------------
__global__ void __launch_bounds__(256, 4)
k_cvtgemm_qkv(const float* __restrict__ wq32, const float* __restrict__ wk32,
              const float* __restrict__ wv32,
              u16* __restrict__ wq16, u16* __restrict__ wk16, u16* __restrict__ wv16,
              const u16* __restrict__ xn, const u16* __restrict__ yn,
              const float* __restrict__ wqb, const float* __restrict__ wkb,
              const float* __restrict__ wvb,
              u16* __restrict__ qo, u16* __restrict__ ko, u16* __restrict__ vT) {
    __shared__ float lds[16 * LP];
    __shared__ float Pl[4][32][16];
    const int kzs = 4, N32 = 16, K = 1024;
    int bx = blockIdx.x, i = blockIdx.y;
    int sel = bx >> 5;
    int bxl = bx & 31;
    int b = bxl & 1, nt = bxl >> 1;
    const float* W32 = (sel == 0 ? wq32 : (sel == 1 ? wk32 : wv32));
    u16* W16 = (sel == 0 ? wq16 : (sel == 1 ? wk16 : wv16));
    const u16* act = (sel == 0 ? xn : yn);
    const float* bias = (sel == 0 ? wqb : (sel == 1 ? wkb : wvb));
    int t = threadIdx.x;
    int w = t >> 6, lane = t & 63;
    int lr = lane & 15, kg = lane >> 4;
    const float* Sp = W32 + ((size_t)(i * N32 + nt) * 32 + b * 16 + (t >> 4)) * K + (t & 15) * 4;
    u16* Dbase = W16 + ((size_t)(i * N32 + nt) * (kzs * 8)) * 1024 + b * 512;
    const u16* A0 = act + ((size_t)(i * 32) + lr) * K + kg * 8;
    const u16* A1 = A0 + (size_t)16 * K;
    f32x4 acc0 = {0.f, 0.f, 0.f, 0.f}, acc1 = {0.f, 0.f, 0.f, 0.f};
    cvtgemm_body(Sp, Dbase, A0, A1, kzs, t, w, lane, lds, acc0, acc1);
#pragma unroll
    for (int rr = 0; rr < 4; ++rr) {
        Pl[w][kg * 4 + rr][lr]      = acc0[rr];
        Pl[w][16 + kg * 4 + rr][lr] = acc1[rr];
    }
    __syncthreads();
    int m = t >> 3, nl0 = (t & 7) * 2;
#pragma unroll
    for (int jj = 0; jj < 2; ++jj) {
        int nl = nl0 + jj;
        float v = Pl[0][m][nl] + Pl[1][m][nl] + Pl[2][m][nl] + Pl[3][m][nl];
        int n = nt * 32 + b * 16 + nl;
        v += bias[i * D512 + n];
        if (sel == 0) {
            qo[(i * 32 + m) * D512 + n] = f2bf(v * QSCALE);
        } else if (sel == 1) {
            ko[(i * 32 + m) * D512 + n] = f2bf(v);
        } else {
            int h = n >> 5, d = n & 31;
            vT[((i * 16 + h) * 32 + d) * 32 + m] = f2bf(v);
        }
    }
}

// swizzled-weight inner loop: p pre-offset by lane*8; 1KB/frag contiguous.
__device__ inline void mmz(const u16* __restrict__ act, const u16* __restrict__ p,
                           int nkk, f32x4& acc0, f32x4& acc1) {
#pragma unroll 4
    for (int j = 0; j < nkk; ++j) {
        bf16x8 aF = *(const bf16x8*)(act + j * 32);
        bf16x8 b0 = *(const bf16x8*)(p + (size_t)j * 1024);
        bf16x8 b1 = *(const bf16x8*)(p + (size_t)j * 1024 + 512);
        acc0 = __builtin_amdgcn_mfma_f32_16x16x32_bf16(aF, b0, acc0, 0, 0, 0);
        acc1 = __builtin_amdgcn_mfma_f32_16x16x32_bf16(aF, b1, acc1, 0, 0, 0);
    }
}

// 256-thread block reduce of (s,q); lds >= 10 floats.
__device__ inline void reduce256(float& s, float& q, int t, float* lds) {
    for (int off = 32; off; off >>= 1) {
        s += __shfl_down(s, off, 64);
        q += __shfl_down(q, off, 64);
    }
    int wv = t >> 6;
    if ((t & 63) == 0) { lds[wv * 2] = s; lds[wv * 2 + 1] = q; }
    __syncthreads();
    if (t == 0) {
        lds[8] = lds[0] + lds[2] + lds[4] + lds[6];
        lds[9] = lds[1] + lds[3] + lds[5] + lds[7];
    }
    __syncthreads();
    s = lds[8]; q = lds[9];
}

// ---- LN1 ------------------------------------------------------------------
__global__ void k_ln1(const float* __restrict__ s1, const float* __restrict__ s2,
                      const float* __restrict__ gw, const float* __restrict__ gb,
                      const float* __restrict__ hw, const float* __restrict__ hb,
                      float* __restrict__ a_buf,
                      u16* __restrict__ xn, u16* __restrict__ yn) {
    __shared__ float lds[10];
    int i = blockIdx.x, cb = blockIdx.y, t = threadIdx.x;
    float s = 0.f, q = 0.f;
#pragma unroll 4
    for (int rr = 0; rr < 32; ++rr) {
        const float* src = (rr < 16)
            ? (s1 + ((i * 16 + rr) << 10))
            : (s2 + (((rr - 16) * 16 + i) << 10));
        f32x4 v = *(const f32x4*)(src + t * 4);
        s += v[0] + v[1] + v[2] + v[3];
        q += v[0]*v[0] + v[1]*v[1] + v[2]*v[2] + v[3]*v[3];
        if ((t >> 5) == cb)
            *(f32x4*)(a_buf + ((i * 32 + rr) << 10) + t * 4) = v;
    }
    reduce256(s, q, t, lds);
    float mean = s * (1.f / NELEM);
    float var = q * (1.f / NELEM) - mean * mean;
    float inv = rsqrtf(var + EPSLN);
    int c = cb * 128 + (t & 31) * 4;
    int r0 = (t >> 5) * 4;
#pragma unroll
    for (int rr = 0; rr < 4; ++rr) {
        int row = r0 + rr;
        const float* src = (row < 16)
            ? (s1 + ((i * 16 + row) << 10))
            : (s2 + (((row - 16) * 16 + i) << 10));
        f32x4 v = *(const f32x4*)(src + c);
        int base = ((i * 32 + row) << 10) + c;
        f32x4 gwv = *(const f32x4*)(gw + base);
        f32x4 gbv = *(const f32x4*)(gb + base);
        f32x4 hwv = *(const f32x4*)(hw + base);
        f32x4 hbv = *(const f32x4*)(hb + base);
        float z0 = (v[0]-mean)*inv, z1 = (v[1]-mean)*inv, z2 = (v[2]-mean)*inv, z3 = (v[3]-mean)*inv;
        uint2 a, b;
        a.x = (unsigned)f2bf(z0*gwv[0]+gbv[0]) | ((unsigned)f2bf(z1*gwv[1]+gbv[1]) << 16);
        a.y = (unsigned)f2bf(z2*gwv[2]+gbv[2]) | ((unsigned)f2bf(z3*gwv[3]+gbv[3]) << 16);
        b.x = (unsigned)f2bf(z0*hwv[0]+hbv[0]) | ((unsigned)f2bf(z1*hwv[1]+hbv[1]) << 16);
        b.y = (unsigned)f2bf(z2*hwv[2]+hbv[2]) | ((unsigned)f2bf(z3*hwv[3]+hbv[3]) << 16);
        *(uint2*)(xn + base) = a;
        *(uint2*)(yn + base) = b;
    }
}

// ---- LN2 ------------------------------------------------------------------
__global__ void k_ln2(const float* __restrict__ x1,
                      const float* __restrict__ gw, const float* __restrict__ gb,
                      u16* __restrict__ out) {
    __shared__ float lds[10];
    int i = blockIdx.x, cb = blockIdx.y, t = threadIdx.x;
    float s = 0.f, q = 0.f;
#pragma unroll 4
    for (int rr = 0; rr < 32; ++rr) {
        f32x4 v = *(const f32x4*)(x1 + ((i * 32 + rr) << 10) + t * 4);
        s += v[0] + v[1] + v[2] + v[3];
        q += v[0]*v[0] + v[1]*v[1] + v[2]*v[2] + v[3]*v[3];
    }
    reduce256(s, q, t, lds);
    float mean = s * (1.f / NELEM);
    float var = q * (1.f / NELEM) - mean * mean;
    float inv = rsqrtf(var + EPSLN);
    int c = cb * 128 + (t & 31) * 4;
    int r0 = (t >> 5) * 4;
#pragma unroll
    for (int rr = 0; rr < 4; ++rr) {
        int base = ((i * 32 + r0 + rr) << 10) + c;
        f32x4 v  = *(const f32x4*)(x1 + base);
        f32x4 gwv = *(const f32x4*)(gw + base);
        f32x4 gbv = *(const f32x4*)(gb + base);
        float z0 = (v[0]-mean)*inv, z1 = (v[1]-mean)*inv, z2 = (v[2]-mean)*inv, z3 = (v[3]-mean)*inv;
        uint2 a;
        a.x = (unsigned)f2bf(z0*gwv[0]+gbv[0]) | ((unsigned)f2bf(z1*gwv[1]+gbv[1]) << 16);
        a.y = (unsigned)f2bf(z2*gwv[2]+gbv[2]) | ((unsigned)f2bf(z3*gwv[3]+gbv[3]) << 16);
        *(uint2*)(out + base) = a;
    }
}

// ---- QKV GEMM (modes 1-2) -------------------------------------------------
__global__ void __launch_bounds__(512, 4)
k_gemm_qkv(const u16* __restrict__ xn, const u16* __restrict__ yn,
           const u16* __restrict__ wq, const float* __restrict__ wqb,
           const u16* __restrict__ wk, const float* __restrict__ wkb,
           const u16* __restrict__ wv, const float* __restrict__ wvb,
           u16* __restrict__ qo, u16* __restrict__ ko, u16* __restrict__ vT) {
    __shared__ float Pl[2][32][64];
    int bx = blockIdx.x, i = blockIdx.y;
    int w = threadIdx.x >> 6, lane = threadIdx.x & 63;
    int kh = w >> 2, mh = (w >> 1) & 1, wn = w & 1;
    int lr = lane & 15, kg = lane >> 4;
    int sel = bx >> 3;
    int ntl = (bx - sel * 8) * 2 + wn;
    const u16* act = (sel == 0 ? xn : yn) + (i * 32 + mh * 16 + lr) * C1024 + kh * 512 + kg * 8;
    const u16* Wm = (sel == 0 ? wq : (sel == 1 ? wk : wv));
    const u16* p = Wm + (((size_t)i * 16 + ntl) * 32 + kh * 16) * 1024 + lane * 8;
    f32x4 a0 = {0.f, 0.f, 0.f, 0.f}, a1 = {0.f, 0.f, 0.f, 0.f};
    mmz(act, p, 16, a0, a1);
    int m0 = mh * 16 + kg * 4;
#pragma unroll
    for (int r = 0; r < 4; ++r) {
        Pl[kh][m0 + r][wn * 32 + lr] = a0[r];
        Pl[kh][m0 + r][wn * 32 + 16 + lr] = a1[r];
    }
    __syncthreads();
    int t = threadIdx.x;
    int row = t >> 4, c0 = (t & 15) * 4;
    int nloc = bx * 64 - sel * 512 + c0;
    const float* bias = (sel == 0 ? wqb : (sel == 1 ? wkb : wvb)) + i * D512 + nloc;
    float v0 = Pl[0][row][c0]     + Pl[1][row][c0]     + bias[0];
    float v1 = Pl[0][row][c0 + 1] + Pl[1][row][c0 + 1] + bias[1];
    float v2 = Pl[0][row][c0 + 2] + Pl[1][row][c0 + 2] + bias[2];
    float v3 = Pl[0][row][c0 + 3] + Pl[1][row][c0 + 3] + bias[3];
    if (sel == 0) {
        uint2 a;
        a.x = (unsigned)f2bf(v0 * QSCALE) | ((unsigned)f2bf(v1 * QSCALE) << 16);
        a.y = (unsigned)f2bf(v2 * QSCALE) | ((unsigned)f2bf(v3 * QSCALE) << 16);
        *(uint2*)(qo + (i * 32 + row) * D512 + nloc) = a;
    } else if (sel == 1) {
        uint2 a;
        a.x = (unsigned)f2bf(v0) | ((unsigned)f2bf(v1) << 16);
        a.y = (unsigned)f2bf(v2) | ((unsigned)f2bf(v3) << 16);
        *(uint2*)(ko + (i * 32 + row) * D512 + nloc) = a;
    } else {
        int h = nloc >> 5, d = nloc & 31;
        u16* vb = vT + ((i * 16 + h) * 32 + d) * 32 + row;
        vb[0]  = f2bf(v0);
        vb[32] = f2bf(v1);
        vb[64] = f2bf(v2);
        vb[96] = f2bf(v3);
    }
}

// ---- attention per (idx, head) --------------------------------------------
__global__ void k_attn(const u16* __restrict__ q, const u16* __restrict__ k,
                       const u16* __restrict__ vT, u16* __restrict__ o) {
    __shared__ __align__(16) u16 Sm[4][32][32];
    int i = blockIdx.x;
    int w = threadIdx.x >> 6, lane = threadIdx.x & 63;
    int h = blockIdx.y * 4 + w;
    int lr = lane & 15, kg = lane >> 4;
    const u16* qb = q + i * 32 * D512 + h * 32 + kg * 8;
    const u16* kb = k + i * 32 * D512 + h * 32 + kg * 8;
    bf16x8 a0 = *(const bf16x8*)(qb + lr * D512);
    bf16x8 a1 = *(const bf16x8*)(qb + (16 + lr) * D512);
    bf16x8 b0 = *(const bf16x8*)(kb + lr * D512);
    bf16x8 b1 = *(const bf16x8*)(kb + (16 + lr) * D512);
    f32x4 z = {0.f, 0.f, 0.f, 0.f};
    f32x4 s00 = __builtin_amdgcn_mfma_f32_16x16x32_bf16(a0, b0, z, 0, 0, 0);
    f32x4 s01 = __builtin_amdgcn_mfma_f32_16x16x32_bf16(a0, b1, z, 0, 0, 0);
    f32x4 s10 = __builtin_amdgcn_mfma_f32_16x16x32_bf16(a1, b0, z, 0, 0, 0);
    f32x4 s11 = __builtin_amdgcn_mfma_f32_16x16x32_bf16(a1, b1, z, 0, 0, 0);
    int mr = kg * 4;
#pragma unroll
    for (int r = 0; r < 4; ++r) {
        Sm[w][mr + r][lr]           = f2bf(s00[r]);
        Sm[w][mr + r][16 + lr]      = f2bf(s01[r]);
        Sm[w][16 + mr + r][lr]      = f2bf(s10[r]);
        Sm[w][16 + mr + r][16 + lr] = f2bf(s11[r]);
    }
    __syncthreads();
    bf16x8 p0 = *(const bf16x8*)&Sm[w][lr][kg * 8];
    bf16x8 p1 = *(const bf16x8*)&Sm[w][16 + lr][kg * 8];
    const u16* vb = vT + (i * 16 + h) * 32 * 32 + kg * 8;
    bf16x8 v0 = *(const bf16x8*)(vb + lr * 32);
    bf16x8 v1 = *(const bf16x8*)(vb + (16 + lr) * 32);
    f32x4 o00 = __builtin_amdgcn_mfma_f32_16x16x32_bf16(p0, v0, z, 0, 0, 0);
    f32x4 o01 = __builtin_amdgcn_mfma_f32_16x16x32_bf16(p0, v1, z, 0, 0, 0);
    f32x4 o10 = __builtin_amdgcn_mfma_f32_16x16x32_bf16(p1, v0, z, 0, 0, 0);
    f32x4 o11 = __builtin_amdgcn_mfma_f32_16x16x32_bf16(p1, v1, z, 0, 0, 0);
#pragma unroll
    for (int r = 0; r < 4; ++r) {
        o[(i * 32 + mr + r) * D512 + h * 32 + lr]           = f2bf(o00[r]);
        o[(i * 32 + mr + r) * D512 + h * 32 + 16 + lr]      = f2bf(o01[r]);
        o[(i * 32 + 16 + mr + r) * D512 + h * 32 + lr]      = f2bf(o10[r]);
        o[(i * 32 + 16 + mr + r) * D512 + h * 32 + 16 + lr] = f2bf(o11[r]);
    }
}

// ---- w1 GEMM (modes 1-2) --------------------------------------------------
__global__ void __launch_bounds__(512, 4)
k_gemm_w1(const u16* __restrict__ ob, const u16* __restrict__ W,
          const float* __restrict__ bias, const float* __restrict__ a_buf,
          float* __restrict__ x1) {
    __shared__ float Pl[2][32][64];
    int bx = blockIdx.x, i = blockIdx.y;
    int w = threadIdx.x >> 6, lane = threadIdx.x & 63;
    int kh = w >> 2, mh = (w >> 1) & 1, wn = w & 1;
    int lr = lane & 15, kg = lane >> 4;
    int nt = bx * 2 + wn;
    const u16* act = ob + (i * 32 + mh * 16 + lr) * D512 + kh * 256 + kg * 8;
    const u16* p = W + (((size_t)i * 32 + nt) * 16 + kh * 8) * 1024 + lane * 8;
    f32x4 a0 = {0.f, 0.f, 0.f, 0.f}, a1 = {0.f, 0.f, 0.f, 0.f};
    mmz(act, p, 8, a0, a1);
    int m0 = mh * 16 + kg * 4;
#pragma unroll
    for (int r = 0; r < 4; ++r) {
        Pl[kh][m0 + r][wn * 32 + lr] = a0[r];
        Pl[kh][m0 + r][wn * 32 + 16 + lr] = a1[r];
    }
    __syncthreads();
    int t = threadIdx.x;
    int row = t >> 4, c0 = (t & 15) * 4;
    int n = bx * 64 + c0;
    int base = ((i * 32 + row) << 10) + n;
    f32x4 bv = *(const f32x4*)(bias + i * C1024 + n);
    f32x4 av = *(const f32x4*)(a_buf + base);
    f32x4 r;
    r[0] = Pl[0][row][c0]     + Pl[1][row][c0]     + bv[0] + av[0];
    r[1] = Pl[0][row][c0 + 1] + Pl[1][row][c0 + 1] + bv[1] + av[1];
    r[2] = Pl[0][row][c0 + 2] + Pl[1][row][c0 + 2] + bv[2] + av[2];
    r[3] = Pl[0][row][c0 + 3] + Pl[1][row][c0 + 3] + bv[3] + av[3];
    *(f32x4*)(x1 + base) = r;
}

// ---- w2 GEMM (modes 1-2) --------------------------------------------------
__global__ void __launch_bounds__(256, 4)
k_gemm_w2(const u16* __restrict__ lnf, const u16* __restrict__ W,
          const float* __restrict__ bias, u16* __restrict__ hb) {
    int bx = blockIdx.x, i = blockIdx.y;
    int w = threadIdx.x >> 6, lane = threadIdx.x & 63;
    int mh = w & 1, wn = w >> 1, lr = lane & 15, kg = lane >> 4;
    int nt = bx * 2 + wn;
    const u16* act = lnf + (i * 32 + mh * 16 + lr) * C1024 + kg * 8;
    const u16* p = W + (((size_t)i * 128 + nt) * 32) * 1024 + lane * 8;
    f32x4 a0 = {0.f, 0.f, 0.f, 0.f}, a1 = {0.f, 0.f, 0.f, 0.f};
    mmz(act, p, 32, a0, a1);
    int m0 = mh * 16 + kg * 4;
    int nb = bx * 64 + wn * 32;
    int n0 = nb + lr, n1 = nb + 16 + lr;
    float b0 = bias[i * FF4096 + n0], b1 = bias[i * FF4096 + n1];
#pragma unroll
    for (int r = 0; r < 4; ++r) {
        float t0 = a0[r] + b0;
        float t1 = a1[r] + b1;
        float g0 = 0.5f * t0 * (1.f + erff(t0 * 0.70710678118654752f));
        float g1 = 0.5f * t1 * (1.f + erff(t1 * 0.70710678118654752f));
        hb[(i * 32 + m0 + r) * FF4096 + n0] = f2bf(g0);
        hb[(i * 32 + m0 + r) * FF4096 + n1] = f2bf(g1);
    }
}

// ---- w3 GEMM (modes 1-2) --------------------------------------------------
__global__ void __launch_bounds__(1024, 4)
k_gemm_w3(const u16* __restrict__ hb, const u16* __restrict__ W,
          const float* __restrict__ bias, const float* __restrict__ x1,
          float* __restrict__ xout, int m1, int m2) {
    __shared__ float Pl[4][32][64];
    int bx = blockIdx.x, i = blockIdx.y;
    int w = threadIdx.x >> 6, lane = threadIdx.x & 63;
    int kq = w >> 2, mh = (w >> 1) & 1, wn = w & 1;
    int lr = lane & 15, kg = lane >> 4;
    int nt = bx * 2 + wn;
    const u16* act = hb + (i * 32 + mh * 16 + lr) * FF4096 + kq * 1024 + kg * 8;
    const u16* p = W + (((size_t)i * 32 + nt) * 128 + kq * 32) * 1024 + lane * 8;
    f32x4 a0 = {0.f, 0.f, 0.f, 0.f}, a1 = {0.f, 0.f, 0.f, 0.f};
    mmz(act, p, 32, a0, a1);
    int m0 = mh * 16 + kg * 4;
#pragma unroll
    for (int r = 0; r < 4; ++r) {
        Pl[kq][m0 + r][wn * 32 + lr] = a0[r];
        Pl[kq][m0 + r][wn * 32 + 16 + lr] = a1[r];
    }
    __syncthreads();
    int t = threadIdx.x;
    int row = t >> 5, c0 = (t & 31) * 2;
    int n = bx * 64 + c0;
    int dst = (row < 16) ? (((m1 * 16 + i) * 16 + row) << 10)
                         : (((m2 * 16 + i) * 16 + (row - 16)) << 10);
    int base = ((i * 32 + row) << 10) + n;
#pragma unroll
    for (int j = 0; j < 2; ++j) {
        float v = Pl[0][row][c0 + j] + Pl[1][row][c0 + j]
                + Pl[2][row][c0 + j] + Pl[3][row][c0 + j]
                + bias[i * C1024 + n + j] + x1[base + j];
        xout[dst + n + j] = v;
    }
}

// ---------------------------------------------------------------------------
extern "C" void kernel_launch(void* const* d_in, const int* in_sizes, int n_in,
                              void* d_out, int out_size, void* d_ws, size_t ws_size,
                              hipStream_t stream) {
    const float* x_in = (const float*)d_in[0];
    const float* lx_w = (const float*)d_in[1];
    const float* lx_b = (const float*)d_in[2];
    const float* ly_w = (const float*)d_in[3];
    const float* ly_b = (const float*)d_in[4];
    const float* lf_w = (const float*)d_in[5];
    const float* lf_b = (const float*)d_in[6];
    const float* wq_w = (const float*)d_in[7];
    const float* wq_b = (const float*)d_in[8];
    const float* wk_w = (const float*)d_in[9];
    const float* wk_b = (const float*)d_in[10];
    const float* wv_w = (const float*)d_in[11];
    const float* wv_b = (const float*)d_in[12];
    const float* w1   = (const float*)d_in[13];
    const float* b1   = (const float*)d_in[14];
    const float* w2   = (const float*)d_in[15];
    const float* b2   = (const float*)d_in[16];
    const float* w3   = (const float*)d_in[17];
    const float* b3   = (const float*)d_in[18];

    float* xbuf = (float*)d_out;   // working state x [3][16][16][1024]
    char* ws = (char*)d_ws;
    float* a_buf  = (float*)(ws);                          //  2 MB @ 0
    float* x1_buf = (float*)(ws + (2u << 20));             //  2 MB @ 2
    u16*   xn     = (u16*)(ws + (4u << 20));               //  1 MB @ 4
    u16*   yn     = (u16*)(ws + (5u << 20));               //  1 MB @ 5
    u16*   lnf    = (u16*)(ws + (6u << 20));               //  1 MB @ 6
    u16*   qb     = (u16*)(ws + (7u << 20));               // .5 MB @ 7
    u16*   kb     = (u16*)(ws + 7 * (1u << 20) + (1u << 19));
    u16*   vT     = (u16*)(ws + (8u << 20));               // .5 MB @ 8
    u16*   ob     = (u16*)(ws + 8 * (1u << 20) + (1u << 19));
    u16*   hbuf   = (u16*)(ws + (9u << 20));               //  4 MB @ 9
    u16*   wq16   = (u16*)(ws + (16u  << 20));             // 16 MB @ 16
    u16*   wk16   = (u16*)(ws + (32u  << 20));             // 16 MB @ 32
    u16*   wv16   = (u16*)(ws + (48u  << 20));             // 16 MB @ 48
    u16*   w1_16  = (u16*)(ws + (64u  << 20));             // 16 MB @ 64
    u16*   w2_16  = (u16*)(ws + (80u  << 20));             // 128 MB @ 80
    u16*   w3_16  = (u16*)(ws + (208u << 20));             // 128 MB @ 208

    const size_t SLAB = (size_t)16 * 16 * 1024;
    const int modes[3][2] = {{0, 1}, {2, 0}, {1, 2}};
    for (int mi = 0; mi < 3; ++mi) {
        int m1 = modes[mi][0], m2 = modes[mi][1];
        const float* s1 = (mi == 2) ? (xbuf + m1 * SLAB) : (x_in + m1 * SLAB);
        const float* s2 = (mi == 0) ? (x_in + m2 * SLAB) : (xbuf + m2 * SLAB);
        k_ln1<<<dim3(16, 8), 256, 0, stream>>>(s1, s2, lx_w, lx_b, ly_w, ly_b, a_buf, xn, yn);
        if (mi == 0) {
            // fused cvt+GEMM: read fp32 weights once, emit bf16 chunks + outputs
            k_cvtgemm_qkv<<<dim3(96, 16), 256, 0, stream>>>(
                wq_w, wk_w, wv_w, wq16, wk16, wv16, xn, yn,
                wq_b, wk_b, wv_b, qb, kb, vT);
            k_attn<<<dim3(16, 4), 256, 0, stream>>>(qb, kb, vT, ob);
            k_cvtgemm<2><<<dim3(64, 16), 256, 0, stream>>>(
                w1, w1_16, ob, 2, 32, b1, nullptr, nullptr, x1_buf, a_buf, 0, 0);
            k_ln2<<<dim3(16, 8), 256, 0, stream>>>(x1_buf, lf_w, lf_b, lnf);
            k_cvtgemm<0><<<dim3(256, 16), 256, 0, stream>>>(
                w2, w2_16, lnf, 4, 128, b2, hbuf, nullptr, nullptr, nullptr, 0, 0);
            k_cvtgemm<1><<<dim3(64, 16), 256, 0, stream>>>(
                w3, w3_16, hbuf, 16, 32, b3, nullptr, x1_buf, xbuf, nullptr, m1, m2);
        } else {
            k_gemm_qkv<<<dim3(24, 16), 512, 0, stream>>>(xn, yn, wq16, wq_b, wk16, wk_b, wv16, wv_b, qb, kb, vT);
            k_attn<<<dim3(16, 4), 256, 0, stream>>>(qb, kb, vT, ob);
            k_gemm_w1<<<dim3(16, 16), 512, 0, stream>>>(ob, w1_16, b1, a_buf, x1_buf);
            k_ln2<<<dim3(16, 8), 256, 0, stream>>>(x1_buf, lf_w, lf_b, lnf);
            k_gemm_w2<<<dim3(64, 16), 256, 0, stream>>>(lnf, w2_16, b2, hbuf);
            k_gemm_w3<<<dim3(16, 16), 1024, 0, stream>>>(hbuf, w3_16, b3, x1_buf, xbuf, m1, m2);
        }
    }
}